// Round 2
// baseline (21305.374 us; speedup 1.0000x reference)
//
#include <hip/hip_runtime.h>
#include <math.h>

// Problem constants: B=8192, NH=128, M=4096, XD=1024
#define ALPHA_1 100.0f
#define SIGMA_1 0.02f

typedef unsigned short bf16_t;   // raw bf16 storage

__device__ __forceinline__ float bf2f(bf16_t u){ return __uint_as_float(((unsigned)u)<<16); }
__device__ __forceinline__ bf16_t f2bf(float f){
  unsigned u = __float_as_uint(f);
  u += 0x7FFFu + ((u>>16)&1u);          // round-to-nearest-even
  return (bf16_t)(u>>16);
}

__device__ __forceinline__ float4 load4f(const float* p){ return *(const float4*)p; }
__device__ __forceinline__ float4 load4f(const bf16_t* p){
  ushort4 u = *(const ushort4*)p;
  float4 r; r.x=bf2f(u.x); r.y=bf2f(u.y); r.z=bf2f(u.z); r.w=bf2f(u.w); return r;
}
__device__ __forceinline__ float loadS(const float* p){ return *p; }
__device__ __forceinline__ float loadS(const bf16_t* p){ return bf2f(*p); }
__device__ __forceinline__ void storeS(float* p, float v){ *p = v; }
__device__ __forceinline__ void storeS(bf16_t* p, float v){ *p = f2bf(v); }

// ---------------------------------------------------------------------------
// Generic tiled GEMM: C(MxN) = alpha*(alpha_ptr?)*op(A)op(B) + beta*C (+bias, relu)
// op(A)=A (M x K) if TRA==0 else Aᵀ with A stored (K x M). Same for B.
// REQUIRES: M%128==0, N%128==0, K%16==0 (all call sites satisfy this).
// fp32 accumulate, 128x128 tile, 256 threads, 8x8 micro-tile.
// NOTE: some call sites alias A/C or B/C in-place; safe because K<=128 there
// (single kk iteration: every global read precedes every write per-block, and
// each block's read set equals its write set).
// ---------------------------------------------------------------------------
template<typename TA, typename TB, typename TC, int TRA, int TRB>
__global__ __launch_bounds__(256) void gemm_kernel(
    int Mm, int Nn, int Kk,
    const TA* __restrict__ A, int lda,
    const TB* __restrict__ B, int ldb,
    TC* __restrict__ C, int ldc,
    float alpha, const float* __restrict__ alpha_ptr,
    float beta, const float* __restrict__ bias, int relu)
{
  __shared__ float As[16][132];   // +4 pad: breaks store bank conflicts
  __shared__ float Bs[16][132];
  const int tid = threadIdx.x;
  const int tx = tid & 15, ty = tid >> 4;
  const int m0 = blockIdx.y << 7, n0 = blockIdx.x << 7;
  float acc[8][8];
#pragma unroll
  for (int i=0;i<8;i++)
#pragma unroll
    for (int j=0;j<8;j++) acc[i][j]=0.0f;

  for (int kk=0; kk<Kk; kk+=16){
#pragma unroll
    for (int l=0;l<2;l++){
      int idx = tid + (l<<8);
      if (TRA==0){
        int r = idx>>2, q = idx&3;
        float4 v = load4f(&A[(size_t)(m0+r)*lda + kk + (q<<2)]);
        As[(q<<2)+0][r]=v.x; As[(q<<2)+1][r]=v.y; As[(q<<2)+2][r]=v.z; As[(q<<2)+3][r]=v.w;
      } else {
        int k = idx>>5, c = (idx&31)<<2;
        float4 v = load4f(&A[(size_t)(kk+k)*lda + m0 + c]);
        *(float4*)&As[k][c] = v;
      }
      if (TRB==0){
        int k = idx>>5, c = (idx&31)<<2;
        float4 v = load4f(&B[(size_t)(kk+k)*ldb + n0 + c]);
        *(float4*)&Bs[k][c] = v;
      } else {
        int r = idx>>2, q = idx&3;
        float4 v = load4f(&B[(size_t)(n0+r)*ldb + kk + (q<<2)]);
        Bs[(q<<2)+0][r]=v.x; Bs[(q<<2)+1][r]=v.y; Bs[(q<<2)+2][r]=v.z; Bs[(q<<2)+3][r]=v.w;
      }
    }
    __syncthreads();
#pragma unroll
    for (int k=0;k<16;k++){
      float a[8], b[8];
      *(float4*)&a[0] = *(const float4*)&As[k][(ty<<3)];
      *(float4*)&a[4] = *(const float4*)&As[k][(ty<<3)+4];
      *(float4*)&b[0] = *(const float4*)&Bs[k][(tx<<3)];
      *(float4*)&b[4] = *(const float4*)&Bs[k][(tx<<3)+4];
#pragma unroll
      for (int i=0;i<8;i++)
#pragma unroll
        for (int j=0;j<8;j++) acc[i][j] = fmaf(a[i], b[j], acc[i][j]);
    }
    __syncthreads();
  }
  float am = alpha;
  if (alpha_ptr) am *= *alpha_ptr;
#pragma unroll
  for (int i=0;i<8;i++){
    int row = m0 + (ty<<3) + i;
#pragma unroll
    for (int j=0;j<8;j++){
      int col = n0 + (tx<<3) + j;
      size_t off = (size_t)row*ldc + col;
      float v = am * acc[i][j];
      if (beta != 0.0f) v = fmaf(beta, loadS(&C[off]), v);
      if (bias) v += bias[col];
      if (relu) v = fmaxf(v, 0.0f);
      storeS(&C[off], v);
    }
  }
}

// ---------------------------------------------------------------------------
// 128x128 Gauss-Jordan inverse, single workgroup of 1024 threads.
// No pivoting: valid because all blocks have symmetric part >= I.
// ---------------------------------------------------------------------------
__global__ __launch_bounds__(1024) void invert128_kernel(
    const float* __restrict__ src, int ld, float* __restrict__ dst)
{
  __shared__ float browA[128], browR[128], fcol[128];
  __shared__ float sPiv;
  int t = threadIdx.x;
  int r = t>>3, sub = t&7;
  int cb = (sub&3)<<5;
  bool isA = sub < 4;
  float own[32];
  if (isA){
#pragma unroll
    for (int i=0;i<32;i++) own[i] = src[(size_t)r*ld + cb + i];
  } else {
#pragma unroll
    for (int i=0;i<32;i++) own[i] = (cb+i == r) ? 1.0f : 0.0f;
  }
  for (int p=0;p<128;p++){
    if (r==p && sub==(p>>5)) sPiv = own[p&31];
    __syncthreads();
    if (r==p){
      float ip = 1.0f / sPiv;
      float* brow = isA ? browA : browR;
#pragma unroll
      for (int i=0;i<32;i++){ own[i] *= ip; brow[cb+i] = own[i]; }
    } else if (sub==(p>>5)){
      fcol[r] = own[p&31];
    }
    __syncthreads();
    if (r != p){
      float f = fcol[r];
      const float* brow = isA ? browA : browR;
#pragma unroll
      for (int i=0;i<32;i++) own[i] = fmaf(-f, brow[cb+i], own[i]);
    }
  }
  if (!isA){
#pragma unroll
    for (int i=0;i<32;i++) dst[(size_t)r*128 + cb + i] = own[i];
  }
}

// ---------------------------------------------------------------------------
// misc small kernels
// ---------------------------------------------------------------------------
__global__ void sumsq_kernel(const float* __restrict__ w, int n, float* __restrict__ acc){
  float s = 0.0f;
  for (int i = blockIdx.x*blockDim.x + threadIdx.x; i < n; i += gridDim.x*blockDim.x){
    float v = w[i]; s = fmaf(v, v, s);
  }
#pragma unroll
  for (int o=32;o;o>>=1) s += __shfl_xor(s, o);
  if ((threadIdx.x & 63) == 0) atomicAdd(acc, s);
}

// scal[0..3]=sumsq(hm,mm,mh,ux) -> scal[4..7]=scale, scal[8..11]=scale^2
__global__ void scales_kernel(float* scal, const float* a0, const float* a1,
                              const float* a2, const float* a3){
  if (threadIdx.x==0 && blockIdx.x==0){
    float s;
    s = a0[0]/sqrtf(scal[0]); scal[4]=s; scal[8]=s*s;
    s = a1[0]/sqrtf(scal[1]); scal[5]=s; scal[9]=s*s;
    s = a2[0]/sqrtf(scal[2]); scal[6]=s; scal[10]=s*s;
    s = a3[0]/sqrtf(scal[3]); scal[7]=s; scal[11]=s*s;
  }
}

// square skew case (W_mm): Mo = I+A, Ro = I-A with A = s(W - Wᵀ)
__global__ void build_mm_kernel(const float* __restrict__ W, const float* __restrict__ scal,
                                float* __restrict__ Mo, float* __restrict__ Ro){
  int j = (blockIdx.x<<4) + (threadIdx.x&15);
  int i = (blockIdx.y<<4) + (threadIdx.x>>4);
  float s = scal[5];
  float a = s*(W[((size_t)i<<12)+j] - W[((size_t)j<<12)+i]);
  float d = (i==j)?1.0f:0.0f;
  size_t o = ((size_t)i<<12)+j;
  Mo[o] = d + a;
  Ro[o] = d - a;
}

// rect case: A = s(U-Uᵀ)+G (G=VᵀV prescaled); Mo(nxn)=I+A, Ro(nx2n)=[I-A | I]
__global__ void build_rect_kernel(const float* __restrict__ W, int ldw, int transw, int n,
      const float* __restrict__ G, const float* __restrict__ scal, int sidx,
      float* __restrict__ Mo, float* __restrict__ Ro){
  int j = (blockIdx.x<<4)+(threadIdx.x&15);
  int i = (blockIdx.y<<4)+(threadIdx.x>>4);
  float s = scal[sidx];
  float wij = transw ? W[(size_t)j*ldw+i] : W[(size_t)i*ldw+j];
  float wji = transw ? W[(size_t)i*ldw+j] : W[(size_t)j*ldw+i];
  float a = s*(wij - wji) + G[(size_t)i*n + j];
  float d = (i==j)?1.0f:0.0f;
  Mo[(size_t)i*n + j] = d + a;
  Ro[(size_t)i*(2*n) + j] = d - a;
  Ro[(size_t)i*(2*n) + n + j] = d;
}

template<typename TD>
__global__ void copy_mat_kernel(const float* __restrict__ src, int lds_,
                                TD* __restrict__ dst, int ldd, int rows, int cols){
  int j = (blockIdx.x<<4)+(threadIdx.x&15);
  int i = (blockIdx.y<<4)+(threadIdx.x>>4);
  if (i<rows && j<cols) storeS(&dst[(size_t)i*ldd+j], src[(size_t)i*lds_+j]);
}

// fp32 -> bf16 elementwise (disjoint buffers)
__global__ void f2bf_kernel(const float* __restrict__ src, bf16_t* __restrict__ dst, int n){
  for (int i = blockIdx.x*blockDim.x + threadIdx.x; i < n; i += gridDim.x*blockDim.x)
    dst[i] = f2bf(src[i]);
}

// simplex-with-floor projection: one wave per row of 128; 30 Newton iters on lam.
__global__ __launch_bounds__(256) void project_kernel(
    const float* __restrict__ ft, const float* __restrict__ h, float* __restrict__ out){
  int row  = (blockIdx.x<<2) + (threadIdx.x>>6);
  int lane = threadIdx.x & 63;
  const float* fr = ft + ((size_t)row<<7);
  const float* hr = h  + ((size_t)row<<7);
  float f0 = fr[lane], f1 = fr[lane+64];
  float l0 = -ALPHA_1*(expf(SIGMA_1*hr[lane])   - 1.0f);
  float l1 = -ALPHA_1*(expf(SIGMA_1*hr[lane+64])- 1.0f);
  float s = f0 + f1;
#pragma unroll
  for (int o=32;o;o>>=1) s += __shfl_xor(s, o);
  float lam = s * (1.0f/128.0f);
  for (int it=0; it<30; it++){
    float a0 = f0 - lam, a1 = f1 - lam;
    float g = fmaxf(a0,l0) + fmaxf(a1,l1);
    float c = (a0>l0 ? 1.0f:0.0f) + (a1>l1 ? 1.0f:0.0f);
#pragma unroll
    for (int o=32;o;o>>=1){ g += __shfl_xor(g,o); c += __shfl_xor(c,o); }
    lam += g / fmaxf(c, 1.0f);   // lam - g/dg with dg = -max(active,1)
  }
  out[((size_t)row<<7)+lane]    = fmaxf(f0-lam, l0);
  out[((size_t)row<<7)+lane+64] = fmaxf(f1-lam, l1);
}

// ---------------------------------------------------------------------------
// host-side helpers (enqueue only)
// ---------------------------------------------------------------------------
template<typename TA, typename TB, typename TC, int TRA, int TRB>
static inline void gemm(hipStream_t st, int Mm, int Nn, int Kk,
    const TA* A, int lda, const TB* B, int ldb, TC* C, int ldc,
    float alpha, const float* aptr, float beta, const float* bias, int relu){
  dim3 grid(Nn>>7, Mm>>7);
  gemm_kernel<TA,TB,TC,TRA,TRB><<<grid, 256, 0, st>>>(Mm,Nn,Kk,A,lda,B,ldb,C,ldc,
                                                      alpha,aptr,beta,bias,relu);
}

// Blocked LU without pivoting (block-Gauss, unit block-diagonal L, Dinv stored).
static void blu_factor(hipStream_t st, float* Mt, int n, float* Dinv){
  int nb = n/128;
  for (int k=0;k<nb;k++){
    invert128_kernel<<<1,1024,0,st>>>(Mt + (size_t)k*128*n + k*128, n,
                                      Dinv + (size_t)k*128*128);
    int rem = n - (k+1)*128;
    if (rem > 0){
      float* panel = Mt + (size_t)(k+1)*128*n + k*128;
      gemm<float,float,float,0,0>(st, rem, 128, 128, panel, n,
          Dinv + (size_t)k*128*128, 128, panel, n, 1.0f,nullptr, 0.0f,nullptr,0);
      gemm<float,float,float,0,0>(st, rem, rem, 128, panel, n,
          Mt + (size_t)k*128*n + (k+1)*128, n,
          Mt + (size_t)(k+1)*128*n + (k+1)*128, n, -1.0f,nullptr, 1.0f,nullptr,0);
    }
  }
}

static void blu_solve(hipStream_t st, const float* Mt, int n, const float* Dinv,
                      float* X, int nrhs, int ldx){
  int nb = n/128;
  for (int k=0;k<nb-1;k++){            // forward (L, unit diag)
    int rem = n-(k+1)*128;
    gemm<float,float,float,0,0>(st, rem, nrhs, 128,
        Mt + (size_t)(k+1)*128*n + k*128, n,
        X + (size_t)k*128*ldx, ldx,
        X + (size_t)(k+1)*128*ldx, ldx, -1.0f,nullptr, 1.0f,nullptr,0);
  }
  for (int k=nb-1;k>=0;k--){           // backward (U)
    gemm<float,float,float,0,0>(st, 128, nrhs, 128,
        Dinv + (size_t)k*128*128, 128,
        X + (size_t)k*128*ldx, ldx,
        X + (size_t)k*128*ldx, ldx, 1.0f,nullptr, 0.0f,nullptr,0);  // in-place ok
    if (k > 0)
      gemm<float,float,float,0,0>(st, k*128, nrhs, 128,
          Mt + k*128, n,
          X + (size_t)k*128*ldx, ldx,
          X, ldx, -1.0f,nullptr, 1.0f,nullptr,0);
  }
}

extern "C" void kernel_launch(void* const* d_in, const int* in_sizes, int n_in,
                              void* d_out, int out_size, void* d_ws, size_t ws_size,
                              hipStream_t stream){
  (void)in_sizes; (void)n_in; (void)out_size; (void)ws_size;
  const float* h    = (const float*)d_in[0];   // 8192x128
  const float* x    = (const float*)d_in[1];   // 8192x1024
  const float* Whm  = (const float*)d_in[2];   // 4096x128
  const float* bhm  = (const float*)d_in[3];   // 4096
  const float* ahm  = (const float*)d_in[4];
  const float* Wmm  = (const float*)d_in[5];   // 4096x4096
  const float* bmm  = (const float*)d_in[6];   // 4096
  const float* amm  = (const float*)d_in[7];
  const float* Wmh  = (const float*)d_in[8];   // 128x4096
  const float* bmh  = (const float*)d_in[9];   // 128
  const float* amh  = (const float*)d_in[10];
  const float* Wux  = (const float*)d_in[11];  // 4096x1024
  const float* bux  = (const float*)d_in[12];  // 4096
  const float* auxs = (const float*)d_in[13];
  float* out = (float*)d_out;

  // ---- workspace layout, peak ~189 MiB (lifetime-aliased) ----
  char* wp = (char*)d_ws;
  auto alloc = [&](size_t bytes)->void*{
    void* p = (void*)wp; wp += (bytes + 255) & ~(size_t)255; return p; };
  float*  scal   = (float*)alloc(16*sizeof(float));
  float*  Ghm    = (float*)alloc((size_t)128*128*4);
  float*  Gmh    = (float*)alloc((size_t)128*128*4);
  float*  Mhm    = (float*)alloc((size_t)128*128*4);
  float*  Mmh    = (float*)alloc((size_t)128*128*4);
  float*  Rhm    = (float*)alloc((size_t)128*256*4);
  float*  Rmh    = (float*)alloc((size_t)128*256*4);
  float*  Dinv   = (float*)alloc((size_t)32*128*128*4);   // 2 MiB
  bf16_t* Qhm    = (bf16_t*)alloc((size_t)4096*128*2);    // 1 MiB
  bf16_t* Qp     = (bf16_t*)alloc((size_t)4096*128*2);    // 1 MiB
  bf16_t* Qux    = (bf16_t*)alloc((size_t)4096*1024*2);   // 8 MiB
  float*  Gux    = (float*)alloc((size_t)1024*1024*4);    // 4 MiB -> later ftl
  float*  Mux    = (float*)alloc((size_t)1024*1024*4);    // 4 MiB
  float*  Rux    = (float*)alloc((size_t)1024*2048*4);    // 8 MiB
  bf16_t* Qmmb   = (bf16_t*)alloc((size_t)4096*4096*2);   // 32 MiB
  float*  R1     = (float*)alloc((size_t)4096*4096*4);    // 64 MiB: Mmm -> z2
  float*  R2     = (float*)alloc((size_t)4096*4096*4);    // 64 MiB: I-A -> Qmm -> z
  // aliases
  float*  Mmm = R1;
  float*  Qmm = R2;                       // fp32 I-A, becomes Q in-place
  bf16_t* z   = (bf16_t*)R2;              // after Qmm converted to bf16
  bf16_t* z2  = (bf16_t*)R1;              // after Mmm LU consumed
  float*  ftl = Gux;                      // 4 MiB, after Gux dead

  // ---- scales s = a / ||W||_F
  hipMemsetAsync(scal, 0, 16*sizeof(float), stream);
  sumsq_kernel<<<512,256,0,stream>>>(Whm, 4096*128,  scal+0);
  sumsq_kernel<<<512,256,0,stream>>>(Wmm, 4096*4096, scal+1);
  sumsq_kernel<<<512,256,0,stream>>>(Wmh, 128*4096,  scal+2);
  sumsq_kernel<<<512,256,0,stream>>>(Wux, 4096*1024, scal+3);
  scales_kernel<<<1,1,0,stream>>>(scal, ahm, amm, amh, auxs);

  // ---- Gram matrices G = (sV)ᵀ(sV)
  gemm<float,float,float,1,0>(stream, 128,128,3968,
      Whm+128*128,128, Whm+128*128,128, Ghm,128, 1.0f,&scal[8], 0.0f,nullptr,0);
  gemm<float,float,float,0,1>(stream, 128,128,3968,
      Wmh+128,4096, Wmh+128,4096, Gmh,128, 1.0f,&scal[10], 0.0f,nullptr,0);
  gemm<float,float,float,1,0>(stream, 1024,1024,3072,
      Wux+(size_t)1024*1024,1024, Wux+(size_t)1024*1024,1024, Gux,1024,
      1.0f,&scal[11], 0.0f,nullptr,0);

  // ---- build I+A / RHS
  build_rect_kernel<<<dim3(8,8),  256,0,stream>>>(Whm, 128,0, 128, Ghm, scal,4, Mhm, Rhm);
  build_rect_kernel<<<dim3(8,8),  256,0,stream>>>(Wmh,4096,1, 128, Gmh, scal,6, Mmh, Rmh);
  build_rect_kernel<<<dim3(64,64),256,0,stream>>>(Wux,1024,0,1024, Gux, scal,7, Mux, Rux);
  build_mm_kernel  <<<dim3(256,256),256,0,stream>>>(Wmm, scal, Mmm, Qmm);

  // ---- Q_hm (bf16 out)
  invert128_kernel<<<1,1024,0,stream>>>(Mhm,128,Dinv);
  gemm<float,float,float,0,0>(stream, 128,256,128, Dinv,128, Rhm,256, Rhm,256,
      1.0f,nullptr, 0.0f,nullptr,0);
  copy_mat_kernel<bf16_t><<<dim3(8,8),256,0,stream>>>(Rhm,256, Qhm,128, 128,128);
  gemm<float,float,bf16_t,0,0>(stream, 3968,128,128, Whm+128*128,128, Rhm+128,256,
      Qhm+(size_t)128*128,128, -2.0f,&scal[4], 0.0f,nullptr,0);

  // ---- Q' = cayley(s*W_mhᵀ) (bf16 out), so f̃ = z2 @ Q'
  invert128_kernel<<<1,1024,0,stream>>>(Mmh,128,Dinv);
  gemm<float,float,float,0,0>(stream, 128,256,128, Dinv,128, Rmh,256, Rmh,256,
      1.0f,nullptr, 0.0f,nullptr,0);
  copy_mat_kernel<bf16_t><<<dim3(8,8),256,0,stream>>>(Rmh,256, Qp,128, 128,128);
  gemm<float,float,bf16_t,1,0>(stream, 3968,128,128, Wmh+128,4096, Rmh+128,256,
      Qp+(size_t)128*128,128, -2.0f,&scal[6], 0.0f,nullptr,0);

  // ---- Q_ux (1024 LU, bf16 out)
  blu_factor(stream, Mux, 1024, Dinv);
  blu_solve (stream, Mux, 1024, Dinv, Rux, 2048, 2048);
  copy_mat_kernel<bf16_t><<<dim3(64,64),256,0,stream>>>(Rux,2048, Qux,1024, 1024,1024);
  gemm<float,float,bf16_t,0,0>(stream, 3072,1024,1024, Wux+(size_t)1024*1024,1024,
      Rux+1024,2048, Qux+(size_t)1024*1024,1024, -2.0f,&scal[7], 0.0f,nullptr,0);

  // ---- Q_mm (4096 LU): Qmm holds I-A, solved in place, then -> bf16
  blu_factor(stream, Mmm, 4096, Dinv);
  blu_solve (stream, Mmm, 4096, Dinv, Qmm, 4096, 4096);
  f2bf_kernel<<<4096,256,0,stream>>>(Qmm, Qmmb, 4096*4096);
  // from here: R2 (Qmm fp32) is dead -> z lives there; R1 (Mmm) dead -> z2.

  // ---- forward (all B operands bf16)
  gemm<float,bf16_t,bf16_t,0,1>(stream, 8192,4096,128,  h,128,  Qhm,128,  z,4096,
      1.0f,nullptr, 0.0f, bhm, 0);
  gemm<float,bf16_t,bf16_t,0,1>(stream, 8192,4096,1024, x,1024, Qux,1024, z,4096,
      1.0f,nullptr, 1.0f, bux, 1);                 // z = relu(hQᵀ+xQᵀ+b+b)
  gemm<bf16_t,bf16_t,bf16_t,0,1>(stream, 8192,4096,4096, z,4096, Qmmb,4096, z2,4096,
      1.0f,nullptr, 0.0f, bmm, 1);                 // z2 = relu(z Qmmᵀ + b)
  gemm<bf16_t,bf16_t,float,0,0>(stream, 8192,128,4096, z2,4096, Qp,128, ftl,128,
      1.0f,nullptr, 0.0f, bmh, 0);                 // f̃ = z2 Q' + b

  // ---- projection
  project_kernel<<<2048,256,0,stream>>>(ftl, h, out);
}

// Round 3
// 18124.411 us; speedup vs baseline: 1.1755x; 1.1755x over previous
//
#include <hip/hip_runtime.h>
#include <math.h>

// Problem: B=8192, NH=128, M=4096, XD=1024
#define ALPHA_1 100.0f
#define SIGMA_1 0.02f

typedef unsigned short bf16_t;   // raw bf16 storage
typedef short  bf16x8  __attribute__((ext_vector_type(8)));   // MFMA A/B frag (8 bf16)
typedef float  floatx4 __attribute__((ext_vector_type(4)));   // MFMA C/D frag

__device__ __forceinline__ float bf2f(bf16_t u){ return __uint_as_float(((unsigned)u)<<16); }
__device__ __forceinline__ bf16_t f2bf(float f){
  unsigned u = __float_as_uint(f);
  u += 0x7FFFu + ((u>>16)&1u);          // RNE
  return (bf16_t)(u>>16);
}

__device__ __forceinline__ float4 load4f(const float* p){ return *(const float4*)p; }
__device__ __forceinline__ float4 load4f(const bf16_t* p){
  ushort4 u = *(const ushort4*)p;
  float4 r; r.x=bf2f(u.x); r.y=bf2f(u.y); r.z=bf2f(u.z); r.w=bf2f(u.w); return r;
}
__device__ __forceinline__ float loadS(const float* p){ return *p; }
__device__ __forceinline__ float loadS(const bf16_t* p){ return bf2f(*p); }
__device__ __forceinline__ void storeS(float* p, float v){ *p = v; }
__device__ __forceinline__ void storeS(bf16_t* p, float v){ *p = f2bf(v); }

// ---------------------------------------------------------------------------
// fp32 VALU GEMM (Cayley path): C = alpha*(aptr?)*op(A)op(B) + beta*C (+bias,relu)
// M%128==0, N%128==0, K%16==0. In-place call sites all have K<=128 (single kk
// iteration; each block's read set == its write set, reads precede writes).
// ---------------------------------------------------------------------------
template<typename TA, typename TB, typename TC, int TRA, int TRB>
__global__ __launch_bounds__(256) void gemm_kernel(
    int Mm, int Nn, int Kk,
    const TA* __restrict__ A, int lda,
    const TB* __restrict__ B, int ldb,
    TC* __restrict__ C, int ldc,
    float alpha, const float* __restrict__ alpha_ptr,
    float beta, const float* __restrict__ bias, int relu)
{
  __shared__ float As[16][132];
  __shared__ float Bs[16][132];
  const int tid = threadIdx.x;
  const int tx = tid & 15, ty = tid >> 4;
  const int m0 = blockIdx.y << 7, n0 = blockIdx.x << 7;
  float acc[8][8];
#pragma unroll
  for (int i=0;i<8;i++)
#pragma unroll
    for (int j=0;j<8;j++) acc[i][j]=0.0f;

  for (int kk=0; kk<Kk; kk+=16){
#pragma unroll
    for (int l=0;l<2;l++){
      int idx = tid + (l<<8);
      if (TRA==0){
        int r = idx>>2, q = idx&3;
        float4 v = load4f(&A[(size_t)(m0+r)*lda + kk + (q<<2)]);
        As[(q<<2)+0][r]=v.x; As[(q<<2)+1][r]=v.y; As[(q<<2)+2][r]=v.z; As[(q<<2)+3][r]=v.w;
      } else {
        int k = idx>>5, c = (idx&31)<<2;
        float4 v = load4f(&A[(size_t)(kk+k)*lda + m0 + c]);
        *(float4*)&As[k][c] = v;
      }
      if (TRB==0){
        int k = idx>>5, c = (idx&31)<<2;
        float4 v = load4f(&B[(size_t)(kk+k)*ldb + n0 + c]);
        *(float4*)&Bs[k][c] = v;
      } else {
        int r = idx>>2, q = idx&3;
        float4 v = load4f(&B[(size_t)(n0+r)*ldb + kk + (q<<2)]);
        Bs[(q<<2)+0][r]=v.x; Bs[(q<<2)+1][r]=v.y; Bs[(q<<2)+2][r]=v.z; Bs[(q<<2)+3][r]=v.w;
      }
    }
    __syncthreads();
#pragma unroll
    for (int k=0;k<16;k++){
      float a[8], b[8];
      *(float4*)&a[0] = *(const float4*)&As[k][(ty<<3)];
      *(float4*)&a[4] = *(const float4*)&As[k][(ty<<3)+4];
      *(float4*)&b[0] = *(const float4*)&Bs[k][(tx<<3)];
      *(float4*)&b[4] = *(const float4*)&Bs[k][(tx<<3)+4];
#pragma unroll
      for (int i=0;i<8;i++)
#pragma unroll
        for (int j=0;j<8;j++) acc[i][j] = fmaf(a[i], b[j], acc[i][j]);
    }
    __syncthreads();
  }
  float am = alpha;
  if (alpha_ptr) am *= *alpha_ptr;
#pragma unroll
  for (int i=0;i<8;i++){
    int row = m0 + (ty<<3) + i;
#pragma unroll
    for (int j=0;j<8;j++){
      int col = n0 + (tx<<3) + j;
      size_t off = (size_t)row*ldc + col;
      float v = am * acc[i][j];
      if (beta != 0.0f) v = fmaf(beta, loadS(&C[off]), v);
      if (bias) v += bias[col];
      if (relu) v = fmaxf(v, 0.0f);
      storeS(&C[off], v);
    }
  }
}

// ---------------------------------------------------------------------------
// bf16 MFMA NT GEMM: C[M][N] = sum_k A[m][k]*B[n][k] + bias[col] (opt relu).
// 128x128 block tile, BK=64, 256 threads (4 waves, each 64x64 = 4x4 mfma
// 16x16x32 tiles). LDS tiles XOR-swizzled so both staging ds_write_b128 and
// fragment ds_read_b128 are bank-balanced (8 lanes per 4-bank group = b128
// floor). M%128==0, N%128==0, K%64==0, lda/ldb%8==0, 16B-aligned pointers.
// ---------------------------------------------------------------------------
template<typename TC, int RELU>
__global__ __launch_bounds__(256) void mfma_nt_kernel(
    int Mm, int Nn, int Kk,
    const bf16_t* __restrict__ A, int lda,
    const bf16_t* __restrict__ B, int ldb,
    TC* __restrict__ C, int ldc,
    const float* __restrict__ bias)
{
  __shared__ bf16_t As[128*64];
  __shared__ bf16_t Bs[128*64];
  const int tid  = threadIdx.x;
  const int lane = tid & 63, wv = tid >> 6;
  const int m0 = (int)(blockIdx.y << 7), n0 = (int)(blockIdx.x << 7);
  const int wm = (wv >> 1) << 6, wn = (wv & 1) << 6;

  floatx4 acc[4][4] = {};

  for (int kk = 0; kk < Kk; kk += 64){
    // ---- stage 128x64 A-tile and B-tile (16B per thread per iter, swizzled)
    uint4 ra[4], rb[4];
#pragma unroll
    for (int i=0;i<4;i++){
      int idx  = (((wv<<2)+i)<<6) | lane;     // 0..1023
      int row  = idx>>3;                      // 0..127
      int cg   = (idx&7) ^ (row&7);           // global chunk for swizzled slot
      ra[i] = *(const uint4*)(A + (size_t)(m0+row)*lda + kk + (cg<<3));
      rb[i] = *(const uint4*)(B + (size_t)(n0+row)*ldb + kk + (cg<<3));
    }
    __syncthreads();                          // previous iter's readers done
#pragma unroll
    for (int i=0;i<4;i++){
      int idx = (((wv<<2)+i)<<6) | lane;
      *(uint4*)&As[idx<<3] = ra[i];
      *(uint4*)&Bs[idx<<3] = rb[i];
    }
    __syncthreads();
    // ---- compute: 2 mfma-K steps of 32
#pragma unroll
    for (int ks=0; ks<2; ks++){
      bf16x8 af[4], bf[4];
      int quad = lane>>4, mr = lane&15;
      int c = quad + (ks<<2);                 // chunk 0..7
#pragma unroll
      for (int i=0;i<4;i++){
        int rowa = wm + i*16 + mr;
        af[i] = *(const bf16x8*)&As[(rowa<<6) + ((c ^ (rowa&7))<<3)];
        int rowb = wn + i*16 + mr;
        bf[i] = *(const bf16x8*)&Bs[(rowb<<6) + ((c ^ (rowb&7))<<3)];
      }
#pragma unroll
      for (int i=0;i<4;i++)
#pragma unroll
        for (int j=0;j<4;j++)
          acc[i][j] = __builtin_amdgcn_mfma_f32_16x16x32_bf16(af[i], bf[j], acc[i][j], 0,0,0);
    }
    __syncthreads();
  }
  // ---- epilogue: C/D layout col=lane&15, row=(lane>>4)*4+reg
#pragma unroll
  for (int i=0;i<4;i++){
#pragma unroll
    for (int j=0;j<4;j++){
      int rbase = m0 + wm + i*16 + (lane>>4)*4;
      int col   = n0 + wn + j*16 + (lane&15);
      float bv = bias ? bias[col] : 0.0f;
#pragma unroll
      for (int r=0;r<4;r++){
        float v = acc[i][j][r] + bv;
        if (RELU) v = fmaxf(v, 0.0f);
        storeS(&C[(size_t)(rbase+r)*ldc + col], v);
      }
    }
  }
}

// ---------------------------------------------------------------------------
// 128x128 Gauss-Jordan inverse (no pivot: symmetric part >= I), 1024 threads.
// ---------------------------------------------------------------------------
__global__ __launch_bounds__(1024) void invert128_kernel(
    const float* __restrict__ src, int ld, float* __restrict__ dst)
{
  __shared__ float browA[128], browR[128], fcol[128];
  __shared__ float sPiv;
  int t = threadIdx.x;
  int r = t>>3, sub = t&7;
  int cb = (sub&3)<<5;
  bool isA = sub < 4;
  float own[32];
  if (isA){
#pragma unroll
    for (int i=0;i<32;i++) own[i] = src[(size_t)r*ld + cb + i];
  } else {
#pragma unroll
    for (int i=0;i<32;i++) own[i] = (cb+i == r) ? 1.0f : 0.0f;
  }
  for (int p=0;p<128;p++){
    if (r==p && sub==(p>>5)) sPiv = own[p&31];
    __syncthreads();
    if (r==p){
      float ip = 1.0f / sPiv;
      float* brow = isA ? browA : browR;
#pragma unroll
      for (int i=0;i<32;i++){ own[i] *= ip; brow[cb+i] = own[i]; }
    } else if (sub==(p>>5)){
      fcol[r] = own[p&31];
    }
    __syncthreads();
    if (r != p){
      float f = fcol[r];
      const float* brow = isA ? browA : browR;
#pragma unroll
      for (int i=0;i<32;i++) own[i] = fmaf(-f, brow[cb+i], own[i]);
    }
  }
  if (!isA){
#pragma unroll
    for (int i=0;i<32;i++) dst[(size_t)r*128 + cb + i] = own[i];
  }
}

// ---------------------------------------------------------------------------
// small kernels
// ---------------------------------------------------------------------------
__global__ void sumsq_kernel(const float* __restrict__ w, int n, float* __restrict__ acc){
  float s = 0.0f;
  for (int i = blockIdx.x*blockDim.x + threadIdx.x; i < n; i += gridDim.x*blockDim.x){
    float v = w[i]; s = fmaf(v, v, s);
  }
#pragma unroll
  for (int o=32;o;o>>=1) s += __shfl_xor(s, o);
  if ((threadIdx.x & 63) == 0) atomicAdd(acc, s);
}

__global__ void scales_kernel(float* scal, const float* a0, const float* a1,
                              const float* a2, const float* a3){
  if (threadIdx.x==0 && blockIdx.x==0){
    float s;
    s = a0[0]/sqrtf(scal[0]); scal[4]=s; scal[8]=s*s;
    s = a1[0]/sqrtf(scal[1]); scal[5]=s; scal[9]=s*s;
    s = a2[0]/sqrtf(scal[2]); scal[6]=s; scal[10]=s*s;
    s = a3[0]/sqrtf(scal[3]); scal[7]=s; scal[11]=s*s;
  }
}

// W_mm square-skew: Mo = I + s(W - W^T)
__global__ void build_mm_kernel(const float* __restrict__ W, const float* __restrict__ scal,
                                float* __restrict__ Mo){
  int j = (blockIdx.x<<4) + (threadIdx.x&15);
  int i = (blockIdx.y<<4) + (threadIdx.x>>4);
  float s = scal[5];
  float a = s*(W[((size_t)i<<12)+j] - W[((size_t)j<<12)+i]);
  Mo[((size_t)i<<12)+j] = ((i==j)?1.0f:0.0f) + a;
}

// rect: Mo = I + s(U-U^T) + G  (G = (sV)^T(sV))
__global__ void build_rect_kernel(const float* __restrict__ W, int ldw, int transw, int n,
      const float* __restrict__ G, const float* __restrict__ scal, int sidx,
      float* __restrict__ Mo){
  int j = (blockIdx.x<<4)+(threadIdx.x&15);
  int i = (blockIdx.y<<4)+(threadIdx.x>>4);
  float s = scal[sidx];
  float wij = transw ? W[(size_t)j*ldw+i] : W[(size_t)i*ldw+j];
  float wji = transw ? W[(size_t)i*ldw+j] : W[(size_t)j*ldw+i];
  Mo[(size_t)i*n + j] = ((i==j)?1.0f:0.0f) + s*(wij - wji) + G[(size_t)i*n + j];
}

__global__ void set_eye_kernel(float* __restrict__ X, int n){
  int j = blockIdx.x*blockDim.x + threadIdx.x;
  int i = blockIdx.y;
  if (j<n) X[(size_t)i*n+j] = (i==j)?1.0f:0.0f;
}

// dst = 2*X - I  (Cayley top / full square Q from inverse)
template<typename TD>
__global__ void qtop_kernel(const float* __restrict__ X, int n,
                            TD* __restrict__ dst, int ldd){
  int j = blockIdx.x*blockDim.x + threadIdx.x;
  int i = blockIdx.y;
  if (j<n) storeS(&dst[(size_t)i*ldd+j],
                  2.0f*X[(size_t)i*n+j] - ((i==j)?1.0f:0.0f));
}

// Qmh_b[n][k] = bf16(QpF[k][n]);  QpF 4096x128 -> Qmh_b 128x4096
__global__ void transpose_bf_kernel(const float* __restrict__ src, bf16_t* __restrict__ dst){
  int k = blockIdx.x*blockDim.x + threadIdx.x;   // 0..4095
  int n = blockIdx.y;                            // 0..127
  if (k < 4096) dst[(size_t)n*4096 + k] = f2bf(src[(size_t)k*128 + n]);
}

// A' = [ bf16(h) | bf16(x) | bf16(x - bf16(x)) ]  (8192 x 2176)
__global__ void pack_A_kernel(const float* __restrict__ h, const float* __restrict__ x,
                              bf16_t* __restrict__ Ap){
  int c = blockIdx.x*blockDim.x + threadIdx.x;
  int m = blockIdx.y;
  if (c >= 2176) return;
  float v;
  if (c < 128)       v = h[(size_t)m*128 + c];
  else if (c < 1152) v = x[(size_t)m*1024 + (c-128)];
  else {
    float xv = x[(size_t)m*1024 + (c-1152)];
    v = xv - bf2f(f2bf(xv));
  }
  Ap[(size_t)m*2176 + c] = f2bf(v);
}

// duplicate B' cols [128,1152) -> [1152,2176)
__global__ void dup_kernel(bf16_t* __restrict__ Bp){
  int c = blockIdx.x*blockDim.x + threadIdx.x;   // 0..1023
  int r = blockIdx.y;
  Bp[(size_t)r*2176 + 1152 + c] = Bp[(size_t)r*2176 + 128 + c];
}

__global__ void addvec_kernel(const float* __restrict__ a, const float* __restrict__ b,
                              float* __restrict__ c, int n){
  int i = blockIdx.x*blockDim.x + threadIdx.x;
  if (i<n) c[i] = a[i] + b[i];
}

// simplex-with-floor projection: one wave per row of 128; 30 Newton iters.
__global__ __launch_bounds__(256) void project_kernel(
    const float* __restrict__ ft, const float* __restrict__ h, float* __restrict__ out){
  int row  = (blockIdx.x<<2) + (threadIdx.x>>6);
  int lane = threadIdx.x & 63;
  const float* fr = ft + ((size_t)row<<7);
  const float* hr = h  + ((size_t)row<<7);
  float f0 = fr[lane], f1 = fr[lane+64];
  float l0 = -ALPHA_1*(expf(SIGMA_1*hr[lane])   - 1.0f);
  float l1 = -ALPHA_1*(expf(SIGMA_1*hr[lane+64])- 1.0f);
  float s = f0 + f1;
#pragma unroll
  for (int o=32;o;o>>=1) s += __shfl_xor(s, o);
  float lam = s * (1.0f/128.0f);
  for (int it=0; it<30; it++){
    float a0 = f0 - lam, a1 = f1 - lam;
    float g = fmaxf(a0,l0) + fmaxf(a1,l1);
    float c = (a0>l0 ? 1.0f:0.0f) + (a1>l1 ? 1.0f:0.0f);
#pragma unroll
    for (int o=32;o;o>>=1){ g += __shfl_xor(g,o); c += __shfl_xor(c,o); }
    lam += g / fmaxf(c, 1.0f);
  }
  out[((size_t)row<<7)+lane]    = fmaxf(f0-lam, l0);
  out[((size_t)row<<7)+lane+64] = fmaxf(f1-lam, l1);
}

// ---------------------------------------------------------------------------
// host-side helpers (enqueue only)
// ---------------------------------------------------------------------------
template<typename TA, typename TB, typename TC, int TRA, int TRB>
static inline void gemm(hipStream_t st, int Mm, int Nn, int Kk,
    const TA* A, int lda, const TB* B, int ldb, TC* C, int ldc,
    float alpha, const float* aptr, float beta, const float* bias, int relu){
  dim3 grid(Nn>>7, Mm>>7);
  gemm_kernel<TA,TB,TC,TRA,TRB><<<grid, 256, 0, st>>>(Mm,Nn,Kk,A,lda,B,ldb,C,ldc,
                                                      alpha,aptr,beta,bias,relu);
}

template<typename TC, int RELU>
static inline void mfma_nt(hipStream_t st, int Mm, int Nn, int Kk,
    const bf16_t* A, int lda, const bf16_t* B, int ldb, TC* C, int ldc,
    const float* bias){
  dim3 grid(Nn>>7, Mm>>7);
  mfma_nt_kernel<TC,RELU><<<grid, 256, 0, st>>>(Mm,Nn,Kk,A,lda,B,ldb,C,ldc,bias);
}

// Blocked LU without pivoting (unit block-diag L, Dinv = diag-block inverses).
static void blu_factor(hipStream_t st, float* Mt, int n, float* Dinv){
  int nb = n/128;
  for (int k=0;k<nb;k++){
    invert128_kernel<<<1,1024,0,st>>>(Mt + (size_t)k*128*n + k*128, n,
                                      Dinv + (size_t)k*128*128);
    int rem = n - (k+1)*128;
    if (rem > 0){
      float* panel = Mt + (size_t)(k+1)*128*n + k*128;
      gemm<float,float,float,0,0>(st, rem, 128, 128, panel, n,
          Dinv + (size_t)k*128*128, 128, panel, n, 1.0f,nullptr, 0.0f,nullptr,0);
      gemm<float,float,float,0,0>(st, rem, rem, 128, panel, n,
          Mt + (size_t)k*128*n + (k+1)*128, n,
          Mt + (size_t)(k+1)*128*n + (k+1)*128, n, -1.0f,nullptr, 1.0f,nullptr,0);
    }
  }
}

// X := (I+A)^-1 from LU factors; X pre-initialized to I.
// Forward sweep restricted to the (triangular) nonzero column range of L^-1.
static void inv_solve(hipStream_t st, const float* Mt, int n, const float* Dinv, float* X){
  int nb = n/128;
  for (int k=0;k<nb-1;k++){
    int rem = n-(k+1)*128, ncols=(k+1)*128;
    gemm<float,float,float,0,0>(st, rem, ncols, 128,
        Mt + (size_t)((k+1)*128)*n + k*128, n,
        X + (size_t)(k*128)*n, n,
        X + (size_t)((k+1)*128)*n, n, -1.0f,nullptr, 1.0f,nullptr,0);
  }
  for (int k=nb-1;k>=0;k--){
    gemm<float,float,float,0,0>(st, 128, n, 128,
        Dinv + (size_t)k*128*128, 128,
        X + (size_t)(k*128)*n, n,
        X + (size_t)(k*128)*n, n, 1.0f,nullptr, 0.0f,nullptr,0);
    if (k>0)
      gemm<float,float,float,0,0>(st, k*128, n, 128,
          Mt + k*128, n,
          X + (size_t)(k*128)*n, n,
          X, n, -1.0f,nullptr, 1.0f,nullptr,0);
  }
}

extern "C" void kernel_launch(void* const* d_in, const int* in_sizes, int n_in,
                              void* d_out, int out_size, void* d_ws, size_t ws_size,
                              hipStream_t stream){
  (void)in_sizes; (void)n_in; (void)out_size; (void)ws_size;
  const float* h    = (const float*)d_in[0];   // 8192x128
  const float* x    = (const float*)d_in[1];   // 8192x1024
  const float* Whm  = (const float*)d_in[2];   // 4096x128
  const float* bhm  = (const float*)d_in[3];
  const float* ahm  = (const float*)d_in[4];
  const float* Wmm  = (const float*)d_in[5];   // 4096x4096
  const float* bmm  = (const float*)d_in[6];
  const float* amm  = (const float*)d_in[7];
  const float* Wmh  = (const float*)d_in[8];   // 128x4096
  const float* bmh  = (const float*)d_in[9];
  const float* amh  = (const float*)d_in[10];
  const float* Wux  = (const float*)d_in[11];  // 4096x1024
  const float* bux  = (const float*)d_in[12];
  const float* auxs = (const float*)d_in[13];
  float* out = (float*)d_out;

  // ---- workspace (~183 MiB peak; 189 MiB proven safe in Round 2) ----
  char* wp = (char*)d_ws;
  auto alloc = [&](size_t bytes)->void*{
    void* p = (void*)wp; wp += (bytes + 255) & ~(size_t)255; return p; };
  float*  scal   = (float*)alloc(4096);
  float*  Ghm    = (float*)alloc((size_t)128*128*4);
  float*  Gmh    = (float*)alloc((size_t)128*128*4);
  float*  Mhm    = (float*)alloc((size_t)128*128*4);
  float*  Mmh    = (float*)alloc((size_t)128*128*4);
  float*  inv128 = (float*)alloc((size_t)128*128*4);
  float*  QpF    = (float*)alloc((size_t)4096*128*4);     // 2 MiB
  bf16_t* Qmh_b  = (bf16_t*)alloc((size_t)128*4096*2);    // 1 MiB
  float*  Dinv   = (float*)alloc((size_t)32*128*128*4);   // 2 MiB
  float*  bsum   = (float*)alloc((size_t)4096*4);
  bf16_t* Bp     = (bf16_t*)alloc((size_t)4096*2176*2);   // 17 MiB [Qhm|Qux|Qux]
  float*  R1     = (float*)alloc((size_t)4096*4096*4);    // 64 MiB
  float*  R2     = (float*)alloc((size_t)4096*4096*4);    // 64 MiB
  bf16_t* Qmmb   = (bf16_t*)alloc((size_t)4096*4096*2);   // 32 MiB
  // lifetime aliases:
  float*  Mmm = R1;                 // LU factors of I+A_mm      (phase 4)
  bf16_t* Ap  = (bf16_t*)R1;        // packed A' concat          (phase 5-6)
  bf16_t* z2  = (bf16_t*)R1;        // GEMM2 out                 (phase 7-8)
  float*  Gux = R2;                 // 4 MiB                     (phase 1)
  float*  Mux = R2 + (size_t)1024*1024;
  float*  Xux = R2 + (size_t)2*1024*1024;
  float*  Xmm = R2;                 // (I+A_mm)^-1 target        (phase 4)
  bf16_t* z   = (bf16_t*)R2;        // GEMM1 out                 (phase 6-7)
  float*  ftl = R2;                 // GEMM3 out (z dead)        (phase 8-9)

  // ---- phase 0: scales s = a/||W||_F
  hipMemsetAsync(scal, 0, 16*sizeof(float), stream);
  sumsq_kernel<<<512,256,0,stream>>>(Whm, 4096*128,  scal+0);
  sumsq_kernel<<<512,256,0,stream>>>(Wmm, 4096*4096, scal+1);
  sumsq_kernel<<<512,256,0,stream>>>(Wmh, 128*4096,  scal+2);
  sumsq_kernel<<<512,256,0,stream>>>(Wux, 4096*1024, scal+3);
  scales_kernel<<<1,1,0,stream>>>(scal, ahm, amm, amh, auxs);

  // ---- phase 1: ux (1024) -> Bp cols [128,1152)
  gemm<float,float,float,1,0>(stream, 1024,1024,3072,
      Wux+(size_t)1024*1024,1024, Wux+(size_t)1024*1024,1024, Gux,1024,
      1.0f,&scal[11], 0.0f,nullptr,0);
  build_rect_kernel<<<dim3(64,64),256,0,stream>>>(Wux,1024,0,1024, Gux, scal,7, Mux);
  set_eye_kernel<<<dim3(4,1024),256,0,stream>>>(Xux, 1024);
  blu_factor(stream, Mux, 1024, Dinv);
  inv_solve (stream, Mux, 1024, Dinv, Xux);
  qtop_kernel<bf16_t><<<dim3(4,1024),256,0,stream>>>(Xux, 1024, Bp+128, 2176);
  gemm<float,float,bf16_t,0,0>(stream, 3072,1024,1024, Wux+(size_t)1024*1024,1024,
      Xux,1024, Bp+(size_t)1024*2176+128, 2176, -2.0f,&scal[7], 0.0f,nullptr,0);

  // ---- phase 2: hm (128) -> Bp cols [0,128)
  gemm<float,float,float,1,0>(stream, 128,128,3968,
      Whm+128*128,128, Whm+128*128,128, Ghm,128, 1.0f,&scal[8], 0.0f,nullptr,0);
  build_rect_kernel<<<dim3(8,8),256,0,stream>>>(Whm,128,0,128, Ghm, scal,4, Mhm);
  invert128_kernel<<<1,1024,0,stream>>>(Mhm,128,inv128);
  qtop_kernel<bf16_t><<<dim3(1,128),256,0,stream>>>(inv128, 128, Bp, 2176);
  gemm<float,float,bf16_t,0,0>(stream, 3968,128,128, Whm+128*128,128,
      inv128,128, Bp+(size_t)128*2176, 2176, -2.0f,&scal[4], 0.0f,nullptr,0);

  // ---- phase 3: mh (128, via W_mh^T) -> QpF (4096x128) -> Qmh_b (128x4096)
  gemm<float,float,float,0,1>(stream, 128,128,3968,
      Wmh+128,4096, Wmh+128,4096, Gmh,128, 1.0f,&scal[10], 0.0f,nullptr,0);
  build_rect_kernel<<<dim3(8,8),256,0,stream>>>(Wmh,4096,1,128, Gmh, scal,6, Mmh);
  invert128_kernel<<<1,1024,0,stream>>>(Mmh,128,inv128);
  qtop_kernel<float><<<dim3(1,128),256,0,stream>>>(inv128, 128, QpF, 128);
  gemm<float,float,float,1,0>(stream, 3968,128,128, Wmh+128,4096,
      inv128,128, QpF+(size_t)128*128, 128, -2.0f,&scal[6], 0.0f,nullptr,0);
  transpose_bf_kernel<<<dim3(16,128),256,0,stream>>>(QpF, Qmh_b);

  // ---- phase 4: mm (4096): LU(I+A) in R1, inverse in R2, Q=2X-I -> bf16
  build_mm_kernel<<<dim3(256,256),256,0,stream>>>(Wmm, scal, Mmm);
  set_eye_kernel<<<dim3(16,4096),256,0,stream>>>(Xmm, 4096);
  blu_factor(stream, Mmm, 4096, Dinv);
  inv_solve (stream, Mmm, 4096, Dinv, Xmm);
  qtop_kernel<bf16_t><<<dim3(16,4096),256,0,stream>>>(Xmm, 4096, Qmmb, 4096);
  // R2 (Xmm) now dead -> z; R1 (Mmm) dead -> Ap.

  // ---- phase 5: pack A' and finish B'
  pack_A_kernel<<<dim3(9,8192),256,0,stream>>>(h, x, Ap);
  dup_kernel<<<dim3(4,4096),256,0,stream>>>(Bp);
  addvec_kernel<<<16,256,0,stream>>>(bhm, bux, bsum, 4096);

  // ---- phases 6-8: forward (bf16 MFMA)
  mfma_nt<bf16_t,1>(stream, 8192,4096,2176, Ap,2176, Bp,2176, z,4096, bsum);
  mfma_nt<bf16_t,1>(stream, 8192,4096,4096, z,4096, Qmmb,4096, z2,4096, bmm);
  mfma_nt<float,0>(stream, 8192, 128,4096, z2,4096, Qmh_b,4096, ftl,128, bmh);

  // ---- phase 9: projection
  project_kernel<<<2048,256,0,stream>>>(ftl, h, out);
}

// Round 4
// 14902.612 us; speedup vs baseline: 1.4296x; 1.2162x over previous
//
#include <hip/hip_runtime.h>
#include <math.h>

// Problem: B=8192, NH=128, M=4096, XD=1024
#define ALPHA_1 100.0f
#define SIGMA_1 0.02f

typedef unsigned short bf16_t;   // raw bf16 storage
typedef short  bf16x8  __attribute__((ext_vector_type(8)));   // MFMA A/B frag
typedef float  floatx4 __attribute__((ext_vector_type(4)));   // MFMA C/D frag

typedef __attribute__((address_space(1))) void glb_void;
typedef __attribute__((address_space(3))) void lds_void;

__device__ __forceinline__ float bf2f(bf16_t u){ return __uint_as_float(((unsigned)u)<<16); }
__device__ __forceinline__ bf16_t f2bf(float f){
  unsigned u = __float_as_uint(f);
  u += 0x7FFFu + ((u>>16)&1u);          // RNE
  return (bf16_t)(u>>16);
}

__device__ __forceinline__ float4 load4f(const float* p){ return *(const float4*)p; }
__device__ __forceinline__ float4 load4f(const bf16_t* p){
  ushort4 u = *(const ushort4*)p;
  float4 r; r.x=bf2f(u.x); r.y=bf2f(u.y); r.z=bf2f(u.z); r.w=bf2f(u.w); return r;
}
__device__ __forceinline__ float loadS(const float* p){ return *p; }
__device__ __forceinline__ float loadS(const bf16_t* p){ return bf2f(*p); }
__device__ __forceinline__ void storeS(float* p, float v){ *p = v; }
__device__ __forceinline__ void storeS(bf16_t* p, float v){ *p = f2bf(v); }

// async 16B global->LDS (gfx950). LDS side is wave-uniform base + lane*16.
__device__ __forceinline__ void async_copy16(void* lds, const void* g){
  __builtin_amdgcn_global_load_lds((glb_void*)g, (lds_void*)lds, 16, 0, 0);
}

// ---------------------------------------------------------------------------
// fp32 VALU GEMM — only for tiny Gram/bottom calls (hm/mh). M%128,N%128,K%16.
// ---------------------------------------------------------------------------
template<typename TA, typename TB, typename TC, int TRA, int TRB>
__global__ __launch_bounds__(256) void gemm_kernel(
    int Mm, int Nn, int Kk,
    const TA* __restrict__ A, int lda,
    const TB* __restrict__ B, int ldb,
    TC* __restrict__ C, int ldc,
    float alpha, const float* __restrict__ alpha_ptr,
    float beta, const float* __restrict__ bias, int relu)
{
  __shared__ float As[16][132];
  __shared__ float Bs[16][132];
  const int tid = threadIdx.x;
  const int tx = tid & 15, ty = tid >> 4;
  const int m0 = blockIdx.y << 7, n0 = blockIdx.x << 7;
  float acc[8][8];
#pragma unroll
  for (int i=0;i<8;i++)
#pragma unroll
    for (int j=0;j<8;j++) acc[i][j]=0.0f;

  for (int kk=0; kk<Kk; kk+=16){
#pragma unroll
    for (int l=0;l<2;l++){
      int idx = tid + (l<<8);
      if (TRA==0){
        int r = idx>>2, q = idx&3;
        float4 v = load4f(&A[(size_t)(m0+r)*lda + kk + (q<<2)]);
        As[(q<<2)+0][r]=v.x; As[(q<<2)+1][r]=v.y; As[(q<<2)+2][r]=v.z; As[(q<<2)+3][r]=v.w;
      } else {
        int k = idx>>5, c = (idx&31)<<2;
        float4 v = load4f(&A[(size_t)(kk+k)*lda + m0 + c]);
        *(float4*)&As[k][c] = v;
      }
      if (TRB==0){
        int k = idx>>5, c = (idx&31)<<2;
        float4 v = load4f(&B[(size_t)(kk+k)*ldb + n0 + c]);
        *(float4*)&Bs[k][c] = v;
      } else {
        int r = idx>>2, q = idx&3;
        float4 v = load4f(&B[(size_t)(n0+r)*ldb + kk + (q<<2)]);
        Bs[(q<<2)+0][r]=v.x; Bs[(q<<2)+1][r]=v.y; Bs[(q<<2)+2][r]=v.z; Bs[(q<<2)+3][r]=v.w;
      }
    }
    __syncthreads();
#pragma unroll
    for (int k=0;k<16;k++){
      float a[8], b[8];
      *(float4*)&a[0] = *(const float4*)&As[k][(ty<<3)];
      *(float4*)&a[4] = *(const float4*)&As[k][(ty<<3)+4];
      *(float4*)&b[0] = *(const float4*)&Bs[k][(tx<<3)];
      *(float4*)&b[4] = *(const float4*)&Bs[k][(tx<<3)+4];
#pragma unroll
      for (int i=0;i<8;i++)
#pragma unroll
        for (int j=0;j<8;j++) acc[i][j] = fmaf(a[i], b[j], acc[i][j]);
    }
    __syncthreads();
  }
  float am = alpha;
  if (alpha_ptr) am *= *alpha_ptr;
#pragma unroll
  for (int i=0;i<8;i++){
    int row = m0 + (ty<<3) + i;
#pragma unroll
    for (int j=0;j<8;j++){
      int col = n0 + (tx<<3) + j;
      size_t off = (size_t)row*ldc + col;
      float v = am * acc[i][j];
      if (beta != 0.0f) v = fmaf(beta, loadS(&C[off]), v);
      if (bias) v += bias[col];
      if (relu) v = fmaxf(v, 0.0f);
      storeS(&C[off], v);
    }
  }
}

// ---------------------------------------------------------------------------
// bf16 MFMA NT GEMM (forward path): C[M][N] = sum_k A[m][k]*B[n][k] + bias.
// 128x128 tile, BK=64, 4 waves of 64x64. global_load_lds(16B) staging with
// per-lane global chunk permutation preserving the XOR LDS swizzle.
// M,N%128==0, K%64==0, rows 16B-aligned.
// ---------------------------------------------------------------------------
template<typename TC, int RELU>
__global__ __launch_bounds__(256) void mfma_nt_kernel(
    int Mm, int Nn, int Kk,
    const bf16_t* __restrict__ A, int lda,
    const bf16_t* __restrict__ B, int ldb,
    TC* __restrict__ C, int ldc,
    const float* __restrict__ bias)
{
  __shared__ bf16_t As[128*64];
  __shared__ bf16_t Bs[128*64];
  const int tid  = threadIdx.x;
  const int lane = tid & 63, wv = tid >> 6;
  const int m0 = (int)(blockIdx.y << 7), n0 = (int)(blockIdx.x << 7);
  const int wm = (wv >> 1) << 6, wn = (wv & 1) << 6;
  const int rbase = wv << 5;                 // 32 rows per wave

  floatx4 acc[4][4] = {};

  for (int kk = 0; kk < Kk; kk += 64){
    __syncthreads();                         // prev iter's readers done
#pragma unroll
    for (int q=0;q<4;q++){
      int row = rbase + (q<<3) + (lane>>3);
      int cg  = (lane&7) ^ (row&7);          // swizzled global chunk
      async_copy16(&As[(size_t)(rbase+(q<<3))<<6],
                   A + (size_t)(m0+row)*lda + kk + (cg<<3));
      async_copy16(&Bs[(size_t)(rbase+(q<<3))<<6],
                   B + (size_t)(n0+row)*ldb + kk + (cg<<3));
    }
    __syncthreads();                         // drains vmcnt before barrier
#pragma unroll
    for (int ks=0; ks<2; ks++){
      bf16x8 af[4], bf[4];
      int quad = lane>>4, mr = lane&15;
      int c = quad + (ks<<2);                // chunk 0..7
#pragma unroll
      for (int i=0;i<4;i++){
        int rowa = wm + i*16 + mr;
        af[i] = *(const bf16x8*)&As[(rowa<<6) + ((c ^ (rowa&7))<<3)];
        int rowb = wn + i*16 + mr;
        bf[i] = *(const bf16x8*)&Bs[(rowb<<6) + ((c ^ (rowb&7))<<3)];
      }
#pragma unroll
      for (int i=0;i<4;i++)
#pragma unroll
        for (int j=0;j<4;j++)
          acc[i][j] = __builtin_amdgcn_mfma_f32_16x16x32_bf16(af[i], bf[j], acc[i][j], 0,0,0);
    }
  }
  // epilogue: C/D layout col=lane&15, row=(lane>>4)*4+reg
#pragma unroll
  for (int i=0;i<4;i++){
#pragma unroll
    for (int j=0;j<4;j++){
      int rbase2 = m0 + wm + i*16 + (lane>>4)*4;
      int col    = n0 + wn + j*16 + (lane&15);
      float bv = bias ? bias[col] : 0.0f;
#pragma unroll
      for (int r=0;r<4;r++){
        float v = acc[i][j][r] + bv;
        if (RELU) v = fmaxf(v, 0.0f);
        storeS(&C[(size_t)(rbase2+r)*ldc + col], v);
      }
    }
  }
}

// ---------------------------------------------------------------------------
// fp32-precision NT GEMM on matrix cores via bf16 hi/lo split (bf16x3):
// C[M][N] = alpha*(aptr?)*sum_k A[m][k]*Bt[n][k] + beta*C.
// A,Bt fp32. 128x128 tile, BK=64. M,N%128==0, K%64==0.
// In-place (C==A or C==Bt) safe at K<=128 call sites: all global reads
// (staging) precede all global writes (epilogue) within a block, and
// in-place call sites have block-unique read/write row sets.
// ---------------------------------------------------------------------------
template<typename TC>
__global__ __launch_bounds__(256) void fgemm_nt_kernel(
    int Mm, int Nn, int Kk,
    const float* __restrict__ A, int lda,
    const float* __restrict__ Bt, int ldb,
    TC* __restrict__ C, int ldc,
    float alpha, const float* __restrict__ alpha_ptr, float beta)
{
  __shared__ bf16_t Ah[128*64], Al[128*64], Bh[128*64], Bl[128*64];
  const int tid = threadIdx.x;
  const int lane = tid & 63, wv = tid >> 6;
  const int m0 = blockIdx.y << 7, n0 = blockIdx.x << 7;
  const int wm = (wv >> 1) << 6, wn = (wv & 1) << 6;
  floatx4 acc[4][4] = {};

  for (int kk = 0; kk < Kk; kk += 64){
    float4 va[8], vb[8];
#pragma unroll
    for (int i=0;i<8;i++){
      int idx = (tid<<3) + i;               // 0..2047
      int row = idx >> 4;                   // 0..127
      int cg  = idx & 15;                   // float4 granule (4 of 64 cols)
      va[i] = load4f(A  + (size_t)(m0+row)*lda + kk + (cg<<2));
      vb[i] = load4f(Bt + (size_t)(n0+row)*ldb + kk + (cg<<2));
    }
    __syncthreads();                        // prev iter's readers done
#pragma unroll
    for (int i=0;i<8;i++){
      int idx = (tid<<3) + i;
      int row = idx >> 4, cg = idx & 15;
      int off = (row<<6) + (((cg>>1) ^ (row&7))<<3) + ((cg&1)<<2);
      bf16_t a0=f2bf(va[i].x), a1=f2bf(va[i].y), a2=f2bf(va[i].z), a3=f2bf(va[i].w);
      ushort4 hv; hv.x=a0; hv.y=a1; hv.z=a2; hv.w=a3;
      ushort4 lv; lv.x=f2bf(va[i].x-bf2f(a0)); lv.y=f2bf(va[i].y-bf2f(a1));
                  lv.z=f2bf(va[i].z-bf2f(a2)); lv.w=f2bf(va[i].w-bf2f(a3));
      *(ushort4*)&Ah[off] = hv; *(ushort4*)&Al[off] = lv;
      bf16_t b0=f2bf(vb[i].x), b1=f2bf(vb[i].y), b2=f2bf(vb[i].z), b3=f2bf(vb[i].w);
      ushort4 hw; hw.x=b0; hw.y=b1; hw.z=b2; hw.w=b3;
      ushort4 lw; lw.x=f2bf(vb[i].x-bf2f(b0)); lw.y=f2bf(vb[i].y-bf2f(b1));
                  lw.z=f2bf(vb[i].z-bf2f(b2)); lw.w=f2bf(vb[i].w-bf2f(b3));
      *(ushort4*)&Bh[off] = hw; *(ushort4*)&Bl[off] = lw;
    }
    __syncthreads();
#pragma unroll
    for (int ks=0; ks<2; ks++){
      int quad = lane>>4, mr = lane&15;
      int c = quad + (ks<<2);
      bf16x8 ah[4], al[4], bh[4], bl[4];
#pragma unroll
      for (int i=0;i<4;i++){
        int rowa = wm + i*16 + mr; int sa = (rowa<<6) + ((c ^ (rowa&7))<<3);
        ah[i] = *(const bf16x8*)&Ah[sa]; al[i] = *(const bf16x8*)&Al[sa];
        int rowb = wn + i*16 + mr; int sb = (rowb<<6) + ((c ^ (rowb&7))<<3);
        bh[i] = *(const bf16x8*)&Bh[sb]; bl[i] = *(const bf16x8*)&Bl[sb];
      }
#pragma unroll
      for (int i=0;i<4;i++)
#pragma unroll
        for (int j=0;j<4;j++){
          acc[i][j] = __builtin_amdgcn_mfma_f32_16x16x32_bf16(ah[i], bl[j], acc[i][j], 0,0,0);
          acc[i][j] = __builtin_amdgcn_mfma_f32_16x16x32_bf16(al[i], bh[j], acc[i][j], 0,0,0);
          acc[i][j] = __builtin_amdgcn_mfma_f32_16x16x32_bf16(ah[i], bh[j], acc[i][j], 0,0,0);
        }
    }
  }
  float am = alpha;
  if (alpha_ptr) am *= *alpha_ptr;
#pragma unroll
  for (int i=0;i<4;i++){
#pragma unroll
    for (int j=0;j<4;j++){
      int rb = m0 + wm + i*16 + (lane>>4)*4;
      int col = n0 + wn + j*16 + (lane&15);
#pragma unroll
      for (int r=0;r<4;r++){
        size_t off = (size_t)(rb+r)*ldc + col;
        float v = am * acc[i][j][r];
        if (beta != 0.0f) v = fmaf(beta, loadS(&C[off]), v);
        storeS(&C[off], v);
      }
    }
  }
}

// ---------------------------------------------------------------------------
// 128x128 Gauss-Jordan inverse (no pivot: symmetric part >= I), 1024 threads.
// Writes inverse AND its transpose.
// ---------------------------------------------------------------------------
__global__ __launch_bounds__(1024) void invert128_kernel(
    const float* __restrict__ src, int ld,
    float* __restrict__ dst, float* __restrict__ dstT)
{
  __shared__ float browA[128], browR[128], fcol[128];
  __shared__ float sPiv;
  int t = threadIdx.x;
  int r = t>>3, sub = t&7;
  int cb = (sub&3)<<5;
  bool isA = sub < 4;
  float own[32];
  if (isA){
#pragma unroll
    for (int i=0;i<32;i++) own[i] = src[(size_t)r*ld + cb + i];
  } else {
#pragma unroll
    for (int i=0;i<32;i++) own[i] = (cb+i == r) ? 1.0f : 0.0f;
  }
  for (int p=0;p<128;p++){
    if (r==p && sub==(p>>5)) sPiv = own[p&31];
    __syncthreads();
    if (r==p){
      float ip = 1.0f / sPiv;
      float* brow = isA ? browA : browR;
#pragma unroll
      for (int i=0;i<32;i++){ own[i] *= ip; brow[cb+i] = own[i]; }
    } else if (sub==(p>>5)){
      fcol[r] = own[p&31];
    }
    __syncthreads();
    if (r != p){
      float f = fcol[r];
      const float* brow = isA ? browA : browR;
#pragma unroll
      for (int i=0;i<32;i++) own[i] = fmaf(-f, brow[cb+i], own[i]);
    }
  }
  if (!isA){
#pragma unroll
    for (int i=0;i<32;i++){
      dst [(size_t)r*128 + cb + i] = own[i];
      dstT[(size_t)(cb+i)*128 + r] = own[i];
    }
  }
}

// ---------------------------------------------------------------------------
// small kernels
// ---------------------------------------------------------------------------
__global__ void sumsq_kernel(const float* __restrict__ w, int n, float* __restrict__ acc){
  float s = 0.0f;
  for (int i = blockIdx.x*blockDim.x + threadIdx.x; i < n; i += gridDim.x*blockDim.x){
    float v = w[i]; s = fmaf(v, v, s);
  }
#pragma unroll
  for (int o=32;o;o>>=1) s += __shfl_xor(s, o);
  if ((threadIdx.x & 63) == 0) atomicAdd(acc, s);
}

__global__ void scales_kernel(float* scal, const float* a0, const float* a1,
                              const float* a2, const float* a3){
  if (threadIdx.x==0 && blockIdx.x==0){
    float s;
    s = a0[0]/sqrtf(scal[0]); scal[4]=s; scal[8]=s*s;
    s = a1[0]/sqrtf(scal[1]); scal[5]=s; scal[9]=s*s;
    s = a2[0]/sqrtf(scal[2]); scal[6]=s; scal[10]=s*s;
    s = a3[0]/sqrtf(scal[3]); scal[7]=s; scal[11]=s*s;
  }
}

__global__ void build_mm_kernel(const float* __restrict__ W, const float* __restrict__ scal,
                                float* __restrict__ Mo){
  int j = (blockIdx.x<<4) + (threadIdx.x&15);
  int i = (blockIdx.y<<4) + (threadIdx.x>>4);
  float s = scal[5];
  float a = s*(W[((size_t)i<<12)+j] - W[((size_t)j<<12)+i]);
  Mo[((size_t)i<<12)+j] = ((i==j)?1.0f:0.0f) + a;
}

__global__ void build_rect_kernel(const float* __restrict__ W, int ldw, int transw, int n,
      const float* __restrict__ G, const float* __restrict__ scal, int sidx,
      float* __restrict__ Mo){
  int j = (blockIdx.x<<4)+(threadIdx.x&15);
  int i = (blockIdx.y<<4)+(threadIdx.x>>4);
  float s = scal[sidx];
  float wij = transw ? W[(size_t)j*ldw+i] : W[(size_t)i*ldw+j];
  float wji = transw ? W[(size_t)i*ldw+j] : W[(size_t)j*ldw+i];
  Mo[(size_t)i*n + j] = ((i==j)?1.0f:0.0f) + s*(wij - wji) + G[(size_t)i*n + j];
}

__global__ void set_eye_kernel(float* __restrict__ X, int n){
  int j = blockIdx.x*blockDim.x + threadIdx.x;
  int i = blockIdx.y;
  if (j<n) X[(size_t)i*n+j] = (i==j)?1.0f:0.0f;
}

// dst = 2*X - I (row-major, no transpose)
template<typename TD>
__global__ void qtop_kernel(const float* __restrict__ X, int n,
                            TD* __restrict__ dst, int ldd){
  int j = blockIdx.x*blockDim.x + threadIdx.x;
  int i = blockIdx.y;
  if (j<n) storeS(&dst[(size_t)i*ldd+j],
                  2.0f*X[(size_t)i*n+j] - ((i==j)?1.0f:0.0f));
}

// fp32 tiled transpose: dst[c][r] = src[r][c]; rows,cols % 32 == 0
__global__ void transposeF_kernel(const float* __restrict__ src, int ls,
                                  float* __restrict__ dst, int ld){
  __shared__ float t[32][33];
  int c0 = blockIdx.x<<5, r0 = blockIdx.y<<5;
  int tx = threadIdx.x & 31, ty = threadIdx.x >> 5;
#pragma unroll
  for (int i=0;i<4;i++) t[ty+i*8][tx] = src[(size_t)(r0+ty+i*8)*ls + c0+tx];
  __syncthreads();
#pragma unroll
  for (int i=0;i<4;i++) dst[(size_t)(c0+ty+i*8)*ld + r0+tx] = t[tx][ty+i*8];
}

// dst[i][j] = bf16(2*Y[j][i] - delta_ij): fused transpose + Cayley-top, n%32==0
__global__ void qtopT_kernel(const float* __restrict__ Y, int n,
                             bf16_t* __restrict__ dst, int ldd){
  __shared__ float t[32][33];
  int c0 = blockIdx.x<<5, r0 = blockIdx.y<<5;
  int tx = threadIdx.x & 31, ty = threadIdx.x >> 5;
#pragma unroll
  for (int i=0;i<4;i++) t[ty+i*8][tx] = Y[(size_t)(r0+ty+i*8)*n + c0+tx];
  __syncthreads();
#pragma unroll
  for (int i=0;i<4;i++){
    int row = c0+ty+i*8, col = r0+tx;
    dst[(size_t)row*ldd + col] = f2bf(2.0f*t[tx][ty+i*8] - ((row==col)?1.0f:0.0f));
  }
}

// Qmh_b[n][k] = bf16(QpF[k][n]);  QpF 4096x128 -> Qmh_b 128x4096
__global__ void transpose_bf_kernel(const float* __restrict__ src, bf16_t* __restrict__ dst){
  int k = blockIdx.x*blockDim.x + threadIdx.x;
  int n = blockIdx.y;
  if (k < 4096) dst[(size_t)n*4096 + k] = f2bf(src[(size_t)k*128 + n]);
}

// A' = [ bf16(h) | bf16(x) | bf16(x - bf16(x)) ]  (8192 x 2176)
__global__ void pack_A_kernel(const float* __restrict__ h, const float* __restrict__ x,
                              bf16_t* __restrict__ Ap){
  int c = blockIdx.x*blockDim.x + threadIdx.x;
  int m = blockIdx.y;
  if (c >= 2176) return;
  float v;
  if (c < 128)       v = h[(size_t)m*128 + c];
  else if (c < 1152) v = x[(size_t)m*1024 + (c-128)];
  else {
    float xv = x[(size_t)m*1024 + (c-1152)];
    v = xv - bf2f(f2bf(xv));
  }
  Ap[(size_t)m*2176 + c] = f2bf(v);
}

__global__ void dup_kernel(bf16_t* __restrict__ Bp){
  int c = blockIdx.x*blockDim.x + threadIdx.x;   // 0..1023
  int r = blockIdx.y;
  Bp[(size_t)r*2176 + 1152 + c] = Bp[(size_t)r*2176 + 128 + c];
}

__global__ void addvec_kernel(const float* __restrict__ a, const float* __restrict__ b,
                              float* __restrict__ c, int n){
  int i = blockIdx.x*blockDim.x + threadIdx.x;
  if (i<n) c[i] = a[i] + b[i];
}

// simplex-with-floor projection: one wave per row of 128; 30 Newton iters.
__global__ __launch_bounds__(256) void project_kernel(
    const float* __restrict__ ft, const float* __restrict__ h, float* __restrict__ out){
  int row  = (blockIdx.x<<2) + (threadIdx.x>>6);
  int lane = threadIdx.x & 63;
  const float* fr = ft + ((size_t)row<<7);
  const float* hr = h  + ((size_t)row<<7);
  float f0 = fr[lane], f1 = fr[lane+64];
  float l0 = -ALPHA_1*(expf(SIGMA_1*hr[lane])   - 1.0f);
  float l1 = -ALPHA_1*(expf(SIGMA_1*hr[lane+64])- 1.0f);
  float s = f0 + f1;
#pragma unroll
  for (int o=32;o;o>>=1) s += __shfl_xor(s, o);
  float lam = s * (1.0f/128.0f);
  for (int it=0; it<30; it++){
    float a0 = f0 - lam, a1 = f1 - lam;
    float g = fmaxf(a0,l0) + fmaxf(a1,l1);
    float c = (a0>l0 ? 1.0f:0.0f) + (a1>l1 ? 1.0f:0.0f);
#pragma unroll
    for (int o=32;o;o>>=1){ g += __shfl_xor(g,o); c += __shfl_xor(c,o); }
    lam += g / fmaxf(c, 1.0f);
  }
  out[((size_t)row<<7)+lane]    = fmaxf(f0-lam, l0);
  out[((size_t)row<<7)+lane+64] = fmaxf(f1-lam, l1);
}

// ---------------------------------------------------------------------------
// host-side helpers (enqueue only)
// ---------------------------------------------------------------------------
template<typename TA, typename TB, typename TC, int TRA, int TRB>
static inline void gemm(hipStream_t st, int Mm, int Nn, int Kk,
    const TA* A, int lda, const TB* B, int ldb, TC* C, int ldc,
    float alpha, const float* aptr, float beta, const float* bias, int relu){
  dim3 grid(Nn>>7, Mm>>7);
  gemm_kernel<TA,TB,TC,TRA,TRB><<<grid, 256, 0, st>>>(Mm,Nn,Kk,A,lda,B,ldb,C,ldc,
                                                      alpha,aptr,beta,bias,relu);
}

template<typename TC, int RELU>
static inline void mfma_nt(hipStream_t st, int Mm, int Nn, int Kk,
    const bf16_t* A, int lda, const bf16_t* B, int ldb, TC* C, int ldc,
    const float* bias){
  dim3 grid(Nn>>7, Mm>>7);
  mfma_nt_kernel<TC,RELU><<<grid, 256, 0, st>>>(Mm,Nn,Kk,A,lda,B,ldb,C,ldc,bias);
}

template<typename TC>
static inline void fgemm(hipStream_t st, int Mm, int Nn, int Kk,
    const float* A, int lda, const float* Bt, int ldb, TC* C, int ldc,
    float alpha, const float* aptr, float beta){
  dim3 grid(Nn>>7, Mm>>7);
  fgemm_nt_kernel<TC><<<grid, 256, 0, st>>>(Mm,Nn,Kk,A,lda,Bt,ldb,C,ldc,alpha,aptr,beta);
}

// Blocked LU without pivoting; all heavy GEMMs on matrix cores (bf16x3 NT).
static void blu_factor(hipStream_t st, float* Mt, int n,
                       float* Dinv, float* DinvT, float* Ut){
  int nb = n/128;
  for (int k=0;k<nb;k++){
    invert128_kernel<<<1,1024,0,st>>>(Mt + (size_t)k*128*n + k*128, n,
                                      Dinv + (size_t)k*16384, DinvT + (size_t)k*16384);
    int rem = n - (k+1)*128;
    if (rem > 0){
      float* panel = Mt + (size_t)(k+1)*128*n + k*128;
      // L = T_panel * Dinv  (NT: Bt = DinvT), in-place
      fgemm<float>(st, rem, 128, 128, panel, n, DinvT + (size_t)k*16384, 128,
                   panel, n, 1.0f, nullptr, 0.0f);
      // Ut = (U row-panel)^T
      transposeF_kernel<<<dim3(rem>>5, 4), 256, 0, st>>>(
          Mt + (size_t)k*128*n + (k+1)*128, n, Ut, 128);
      // Schur: T -= L * U  (NT: Bt = Ut)
      fgemm<float>(st, rem, rem, 128, panel, n, Ut, 128,
                   Mt + (size_t)(k+1)*128*n + (k+1)*128, n, -1.0f, nullptr, 1.0f);
    }
  }
}

// Y := ((I+A)^-1)^T from LU factors; Y pre-initialized to I. All NT fgemms.
static void inv_solve_Y(hipStream_t st, const float* Mt, int n,
                        const float* Dinv, float* Y){
  int nb = n/128;
  for (int k=0;k<nb-1;k++){               // forward (columns of Y)
    int rows=(k+1)*128, rem=n-(k+1)*128;
    fgemm<float>(st, rows, rem, 128,
        Y + k*128, n,                                  // A: rows x 128
        Mt + (size_t)(k+1)*128*n + k*128, n,           // Bt: L col-panel rem x 128
        Y + (k+1)*128, n, -1.0f, nullptr, 1.0f);       // C: rows x rem
  }
  for (int k=nb-1;k>=0;k--){              // backward
    fgemm<float>(st, n, 128, 128,
        Y + k*128, n, Dinv + (size_t)k*16384, 128,     // Bt = Dinv (gives *Dinv^T)
        Y + k*128, n, 1.0f, nullptr, 0.0f);            // in-place
    if (k>0)
      fgemm<float>(st, n, k*128, 128,
          Y + k*128, n, Mt + k*128, n,                 // Bt: U col-panel k*128 x 128
          Y, n, -1.0f, nullptr, 1.0f);
  }
}

extern "C" void kernel_launch(void* const* d_in, const int* in_sizes, int n_in,
                              void* d_out, int out_size, void* d_ws, size_t ws_size,
                              hipStream_t stream){
  (void)in_sizes; (void)n_in; (void)out_size; (void)ws_size;
  const float* h    = (const float*)d_in[0];   // 8192x128
  const float* x    = (const float*)d_in[1];   // 8192x1024
  const float* Whm  = (const float*)d_in[2];   // 4096x128
  const float* bhm  = (const float*)d_in[3];
  const float* ahm  = (const float*)d_in[4];
  const float* Wmm  = (const float*)d_in[5];   // 4096x4096
  const float* bmm  = (const float*)d_in[6];
  const float* amm  = (const float*)d_in[7];
  const float* Wmh  = (const float*)d_in[8];   // 128x4096
  const float* bmh  = (const float*)d_in[9];
  const float* amh  = (const float*)d_in[10];
  const float* Wux  = (const float*)d_in[11];  // 4096x1024
  const float* bux  = (const float*)d_in[12];
  const float* auxs = (const float*)d_in[13];
  float* out = (float*)d_out;

  // ---- workspace (~186 MiB peak; 189 MiB proven safe in Round 2) ----
  char* wp = (char*)d_ws;
  auto alloc = [&](size_t bytes)->void*{
    void* p = (void*)wp; wp += (bytes + 255) & ~(size_t)255; return p; };
  float*  scal    = (float*)alloc(4096);
  float*  Ghm     = (float*)alloc((size_t)128*128*4);
  float*  Gmh     = (float*)alloc((size_t)128*128*4);
  float*  Mhm     = (float*)alloc((size_t)128*128*4);
  float*  Mmh     = (float*)alloc((size_t)128*128*4);
  float*  inv128  = (float*)alloc((size_t)128*128*4);
  float*  inv128T = (float*)alloc((size_t)128*128*4);
  float*  QpF     = (float*)alloc((size_t)4096*128*4);     // 2 MiB
  bf16_t* Qmh_b   = (bf16_t*)alloc((size_t)128*4096*2);    // 1 MiB
  float*  Dinv    = (float*)alloc((size_t)32*16384*4);     // 2 MiB
  float*  DinvT   = (float*)alloc((size_t)32*16384*4);     // 2 MiB
  float*  Ut      = (float*)alloc((size_t)3968*128*4);     // 2 MiB
  float*  bsum    = (float*)alloc((size_t)4096*4);
  bf16_t* Bp      = (bf16_t*)alloc((size_t)4096*2176*2);   // 17 MiB [Qhm|Qux|Qux_dup]
  float*  R1      = (float*)alloc((size_t)4096*4096*4);    // 64 MiB
  float*  R2      = (float*)alloc((size_t)4096*4096*4);    // 64 MiB
  bf16_t* Qmmb    = (bf16_t*)alloc((size_t)4096*4096*2);   // 32 MiB
  // lifetime aliases:
  float*  Mmm = R1;                             // LU of I+A_mm   (phase 4)
  bf16_t* Ap  = (bf16_t*)R1;                    // packed A'      (phase 5-6)
  bf16_t* z2  = (bf16_t*)R1;                    // GEMM2 out      (phase 7-8)
  float*  Gux = R2;                             // phase 1 carve of R2:
  float*  Mux = R2 + (size_t)1024*1024;
  float*  Yux = R2 + (size_t)2*1024*1024;
  float*  VT  = R2 + (size_t)3*1024*1024;       // 12 MiB (1024x3072)
  float*  Ymm = R2;                             // ((I+A_mm)^-1)^T (phase 4)
  bf16_t* z   = (bf16_t*)R2;                    // GEMM1 out      (phase 6-7)
  float*  ftl = R2;                             // GEMM3 out      (phase 8-9)

  // ---- phase 0: scales s = a/||W||_F
  hipMemsetAsync(scal, 0, 16*sizeof(float), stream);
  sumsq_kernel<<<512,256,0,stream>>>(Whm, 4096*128,  scal+0);
  sumsq_kernel<<<512,256,0,stream>>>(Wmm, 4096*4096, scal+1);
  sumsq_kernel<<<512,256,0,stream>>>(Wmh, 128*4096,  scal+2);
  sumsq_kernel<<<512,256,0,stream>>>(Wux, 4096*1024, scal+3);
  scales_kernel<<<1,1,0,stream>>>(scal, ahm, amm, amh, auxs);

  // ---- phase 1: ux (1024) -> Bp cols [128,1152)
  transposeF_kernel<<<dim3(32,96),256,0,stream>>>(Wux+(size_t)1024*1024, 1024, VT, 3072);
  fgemm<float>(stream, 1024,1024,3072, VT,3072, VT,3072, Gux,1024,
               1.0f,&scal[11], 0.0f);                       // G = s^2 V^T V
  build_rect_kernel<<<dim3(64,64),256,0,stream>>>(Wux,1024,0,1024, Gux, scal,7, Mux);
  set_eye_kernel<<<dim3(4,1024),256,0,stream>>>(Yux, 1024);
  blu_factor(stream, Mux, 1024, Dinv, DinvT, Ut);
  inv_solve_Y(stream, Mux, 1024, Dinv, Yux);
  qtopT_kernel<<<dim3(32,32),256,0,stream>>>(Yux, 1024, Bp+128, 2176);
  fgemm<bf16_t>(stream, 3072,1024,1024, Wux+(size_t)1024*1024,1024, Yux,1024,
                Bp+(size_t)1024*2176+128, 2176, -2.0f,&scal[7], 0.0f);

  // ---- phase 2: hm (128) -> Bp cols [0,128)
  gemm<float,float,float,1,0>(stream, 128,128,3968,
      Whm+128*128,128, Whm+128*128,128, Ghm,128, 1.0f,&scal[8], 0.0f,nullptr,0);
  build_rect_kernel<<<dim3(8,8),256,0,stream>>>(Whm,128,0,128, Ghm, scal,4, Mhm);
  invert128_kernel<<<1,1024,0,stream>>>(Mhm,128,inv128,inv128T);
  qtop_kernel<bf16_t><<<dim3(1,128),256,0,stream>>>(inv128, 128, Bp, 2176);
  fgemm<bf16_t>(stream, 3968,128,128, Whm+128*128,128, inv128T,128,
                Bp+(size_t)128*2176, 2176, -2.0f,&scal[4], 0.0f);

  // ---- phase 3: mh (128, via W_mh^T) -> QpF -> Qmh_b
  gemm<float,float,float,0,1>(stream, 128,128,3968,
      Wmh+128,4096, Wmh+128,4096, Gmh,128, 1.0f,&scal[10], 0.0f,nullptr,0);
  build_rect_kernel<<<dim3(8,8),256,0,stream>>>(Wmh,4096,1,128, Gmh, scal,6, Mmh);
  invert128_kernel<<<1,1024,0,stream>>>(Mmh,128,inv128,inv128T);
  qtop_kernel<float><<<dim3(1,128),256,0,stream>>>(inv128, 128, QpF, 128);
  gemm<float,float,float,1,0>(stream, 3968,128,128, Wmh+128,4096,
      inv128,128, QpF+(size_t)128*128, 128, -2.0f,&scal[6], 0.0f,nullptr,0);
  transpose_bf_kernel<<<dim3(16,128),256,0,stream>>>(QpF, Qmh_b);

  // ---- phase 4: mm (4096): LU in R1, Y=(inv)^T in R2, Qmmb = (2Y^T - I) bf16
  build_mm_kernel<<<dim3(256,256),256,0,stream>>>(Wmm, scal, Mmm);
  set_eye_kernel<<<dim3(16,4096),256,0,stream>>>(Ymm, 4096);
  blu_factor(stream, Mmm, 4096, Dinv, DinvT, Ut);
  inv_solve_Y(stream, Mmm, 4096, Dinv, Ymm);
  qtopT_kernel<<<dim3(128,128),256,0,stream>>>(Ymm, 4096, Qmmb, 4096);
  // R2 (Ymm) now dead -> z; R1 (Mmm) dead -> Ap.

  // ---- phase 5: pack A', finish B', bias sum
  pack_A_kernel<<<dim3(9,8192),256,0,stream>>>(h, x, Ap);
  dup_kernel<<<dim3(4,4096),256,0,stream>>>(Bp);
  addvec_kernel<<<16,256,0,stream>>>(bhm, bux, bsum, 4096);

  // ---- phases 6-8: forward (bf16 MFMA, async LDS staging)
  mfma_nt<bf16_t,1>(stream, 8192,4096,2176, Ap,2176, Bp,2176, z,4096, bsum);
  mfma_nt<bf16_t,1>(stream, 8192,4096,4096, z,4096, Qmmb,4096, z2,4096, bmm);
  mfma_nt<float,0>(stream, 8192, 128,4096, z2,4096, Qmh_b,4096, ftl,128, bmh);

  // ---- phase 9: projection
  project_kernel<<<2048,256,0,stream>>>(ftl, h, out);
}

// Round 5
// 13168.385 us; speedup vs baseline: 1.6179x; 1.1317x over previous
//
#include <hip/hip_runtime.h>
#include <math.h>

// Problem: B=8192, NH=128, M=4096, XD=1024
#define ALPHA_1 100.0f
#define SIGMA_1 0.02f

typedef unsigned short bf16_t;   // raw bf16 storage
typedef short  bf16x8  __attribute__((ext_vector_type(8)));   // MFMA A/B frag
typedef float  floatx4 __attribute__((ext_vector_type(4)));   // MFMA C/D frag

typedef __attribute__((address_space(1))) void glb_void;
typedef __attribute__((address_space(3))) void lds_void;

__device__ __forceinline__ float bf2f(bf16_t u){ return __uint_as_float(((unsigned)u)<<16); }
__device__ __forceinline__ bf16_t f2bf(float f){
  unsigned u = __float_as_uint(f);
  u += 0x7FFFu + ((u>>16)&1u);          // RNE
  return (bf16_t)(u>>16);
}

__device__ __forceinline__ float4 load4f(const float* p){ return *(const float4*)p; }
__device__ __forceinline__ float loadS(const float* p){ return *p; }
__device__ __forceinline__ float loadS(const bf16_t* p){ return bf2f(*p); }
__device__ __forceinline__ void storeS(float* p, float v){ *p = v; }
__device__ __forceinline__ void storeS(bf16_t* p, float v){ *p = f2bf(v); }

// async 16B global->LDS (gfx950). LDS side is wave-uniform base + lane*16.
__device__ __forceinline__ void async_copy16(void* lds, const void* g){
  __builtin_amdgcn_global_load_lds((glb_void*)g, (lds_void*)lds, 16, 0, 0);
}

// ---------------------------------------------------------------------------
// bf16 MFMA NT GEMM (forward path): C[M][N] = sum_k A[m][k]*B[n][k] + bias.
// 128x128 tile, BK=64, 4 waves of 64x64. global_load_lds(16B) staging with
// per-lane chunk permutation preserving the XOR LDS swizzle.
// ---------------------------------------------------------------------------
template<typename TC, int RELU>
__global__ __launch_bounds__(256) void mfma_nt_kernel(
    int Mm, int Nn, int Kk,
    const bf16_t* __restrict__ A, int lda,
    const bf16_t* __restrict__ B, int ldb,
    TC* __restrict__ C, int ldc,
    const float* __restrict__ bias)
{
  __shared__ bf16_t As[128*64];
  __shared__ bf16_t Bs[128*64];
  const int tid  = threadIdx.x;
  const int lane = tid & 63, wv = tid >> 6;
  const int m0 = (int)(blockIdx.y << 7), n0 = (int)(blockIdx.x << 7);
  const int wm = (wv >> 1) << 6, wn = (wv & 1) << 6;
  const int rbase = wv << 5;                 // 32 rows per wave

  floatx4 acc[4][4] = {};

  for (int kk = 0; kk < Kk; kk += 64){
    __syncthreads();                         // prev iter's readers done
#pragma unroll
    for (int q=0;q<4;q++){
      int row = rbase + (q<<3) + (lane>>3);
      int cg  = (lane&7) ^ (row&7);          // swizzled global chunk
      async_copy16(&As[(size_t)(rbase+(q<<3))<<6],
                   A + (size_t)(m0+row)*lda + kk + (cg<<3));
      async_copy16(&Bs[(size_t)(rbase+(q<<3))<<6],
                   B + (size_t)(n0+row)*ldb + kk + (cg<<3));
    }
    __syncthreads();
#pragma unroll
    for (int ks=0; ks<2; ks++){
      bf16x8 af[4], bf[4];
      int quad = lane>>4, mr = lane&15;
      int c = quad + (ks<<2);                // chunk 0..7
#pragma unroll
      for (int i=0;i<4;i++){
        int rowa = wm + i*16 + mr;
        af[i] = *(const bf16x8*)&As[(rowa<<6) + ((c ^ (rowa&7))<<3)];
        int rowb = wn + i*16 + mr;
        bf[i] = *(const bf16x8*)&Bs[(rowb<<6) + ((c ^ (rowb&7))<<3)];
      }
#pragma unroll
      for (int i=0;i<4;i++)
#pragma unroll
        for (int j=0;j<4;j++)
          acc[i][j] = __builtin_amdgcn_mfma_f32_16x16x32_bf16(af[i], bf[j], acc[i][j], 0,0,0);
    }
  }
#pragma unroll
  for (int i=0;i<4;i++){
#pragma unroll
    for (int j=0;j<4;j++){
      int rbase2 = m0 + wm + i*16 + (lane>>4)*4;
      int col    = n0 + wn + j*16 + (lane&15);
      float bv = bias ? bias[col] : 0.0f;
#pragma unroll
      for (int r=0;r<4;r++){
        float v = acc[i][j][r] + bv;
        if (RELU) v = fmaxf(v, 0.0f);
        storeS(&C[(size_t)(rbase2+r)*ldc + col], v);
      }
    }
  }
}

// ---------------------------------------------------------------------------
// fp32-precision NT GEMM on matrix cores via bf16 hi/lo split (bf16x3):
// C[M][N] = alpha*(aptr?)*sum_k A[m][k]*Bt[n][k] + beta*C.
// 128x128 tile, BK=64. M,N%128==0, K%64==0. skipk: M-block-row to skip
// (grid.y = M/128 - 1 then), pass >=M/128 for a full grid.
// No A/B/C aliasing at any call site.
// ---------------------------------------------------------------------------
template<typename TC>
__global__ __launch_bounds__(256) void fgemm_nt_kernel(
    int Mm, int Nn, int Kk,
    const float* __restrict__ A, int lda,
    const float* __restrict__ Bt, int ldb,
    TC* __restrict__ C, int ldc,
    float alpha, const float* __restrict__ alpha_ptr, float beta, int skipk)
{
  __shared__ bf16_t Ah[128*64], Al[128*64], Bh[128*64], Bl[128*64];
  const int tid = threadIdx.x;
  const int lane = tid & 63, wv = tid >> 6;
  int by = blockIdx.y; if (by >= skipk) by++;
  const int m0 = by << 7, n0 = blockIdx.x << 7;
  const int wm = (wv >> 1) << 6, wn = (wv & 1) << 6;
  floatx4 acc[4][4] = {};

  for (int kk = 0; kk < Kk; kk += 64){
    float4 va[8], vb[8];
#pragma unroll
    for (int i=0;i<8;i++){
      int idx = (tid<<3) + i;               // 0..2047
      int row = idx >> 4;                   // 0..127
      int cg  = idx & 15;                   // float4 granule
      va[i] = load4f(A  + (size_t)(m0+row)*lda + kk + (cg<<2));
      vb[i] = load4f(Bt + (size_t)(n0+row)*ldb + kk + (cg<<2));
    }
    __syncthreads();
#pragma unroll
    for (int i=0;i<8;i++){
      int idx = (tid<<3) + i;
      int row = idx >> 4, cg = idx & 15;
      int off = (row<<6) + (((cg>>1) ^ (row&7))<<3) + ((cg&1)<<2);
      bf16_t a0=f2bf(va[i].x), a1=f2bf(va[i].y), a2=f2bf(va[i].z), a3=f2bf(va[i].w);
      ushort4 hv; hv.x=a0; hv.y=a1; hv.z=a2; hv.w=a3;
      ushort4 lv; lv.x=f2bf(va[i].x-bf2f(a0)); lv.y=f2bf(va[i].y-bf2f(a1));
                  lv.z=f2bf(va[i].z-bf2f(a2)); lv.w=f2bf(va[i].w-bf2f(a3));
      *(ushort4*)&Ah[off] = hv; *(ushort4*)&Al[off] = lv;
      bf16_t b0=f2bf(vb[i].x), b1=f2bf(vb[i].y), b2=f2bf(vb[i].z), b3=f2bf(vb[i].w);
      ushort4 hw; hw.x=b0; hw.y=b1; hw.z=b2; hw.w=b3;
      ushort4 lw; lw.x=f2bf(vb[i].x-bf2f(b0)); lw.y=f2bf(vb[i].y-bf2f(b1));
                  lw.z=f2bf(vb[i].z-bf2f(b2)); lw.w=f2bf(vb[i].w-bf2f(b3));
      *(ushort4*)&Bh[off] = hw; *(ushort4*)&Bl[off] = lw;
    }
    __syncthreads();
#pragma unroll
    for (int ks=0; ks<2; ks++){
      int quad = lane>>4, mr = lane&15;
      int c = quad + (ks<<2);
      bf16x8 ah[4], al[4], bh[4], bl[4];
#pragma unroll
      for (int i=0;i<4;i++){
        int rowa = wm + i*16 + mr; int sa = (rowa<<6) + ((c ^ (rowa&7))<<3);
        ah[i] = *(const bf16x8*)&Ah[sa]; al[i] = *(const bf16x8*)&Al[sa];
        int rowb = wn + i*16 + mr; int sb = (rowb<<6) + ((c ^ (rowb&7))<<3);
        bh[i] = *(const bf16x8*)&Bh[sb]; bl[i] = *(const bf16x8*)&Bl[sb];
      }
#pragma unroll
      for (int i=0;i<4;i++)
#pragma unroll
        for (int j=0;j<4;j++){
          acc[i][j] = __builtin_amdgcn_mfma_f32_16x16x32_bf16(ah[i], bl[j], acc[i][j], 0,0,0);
          acc[i][j] = __builtin_amdgcn_mfma_f32_16x16x32_bf16(al[i], bh[j], acc[i][j], 0,0,0);
          acc[i][j] = __builtin_amdgcn_mfma_f32_16x16x32_bf16(ah[i], bh[j], acc[i][j], 0,0,0);
        }
    }
    __syncthreads();
  }
  float am = alpha;
  if (alpha_ptr) am *= *alpha_ptr;
#pragma unroll
  for (int i=0;i<4;i++){
#pragma unroll
    for (int j=0;j<4;j++){
      int rb = m0 + wm + i*16 + (lane>>4)*4;
      int col = n0 + wn + j*16 + (lane&15);
#pragma unroll
      for (int r=0;r<4;r++){
        size_t off = (size_t)(rb+r)*ldc + col;
        float v = am * acc[i][j][r];
        if (beta != 0.0f) v = fmaf(beta, loadS(&C[off]), v);
        storeS(&C[off], v);
      }
    }
  }
}

// ---------------------------------------------------------------------------
// 128x128 Gauss-Jordan inverse (no pivot: symmetric part >= I), 1024 threads.
// Writes inverse AND its transpose.
// ---------------------------------------------------------------------------
__global__ __launch_bounds__(1024) void invert128_kernel(
    const float* __restrict__ src, int ld,
    float* __restrict__ dst, float* __restrict__ dstT)
{
  __shared__ float browA[128], browR[128], fcol[128];
  __shared__ float sPiv;
  int t = threadIdx.x;
  int r = t>>3, sub = t&7;
  int cb = (sub&3)<<5;
  bool isA = sub < 4;
  float own[32];
  if (isA){
#pragma unroll
    for (int i=0;i<32;i++) own[i] = src[(size_t)r*ld + cb + i];
  } else {
#pragma unroll
    for (int i=0;i<32;i++) own[i] = (cb+i == r) ? 1.0f : 0.0f;
  }
  for (int p=0;p<128;p++){
    if (r==p && sub==(p>>5)) sPiv = own[p&31];
    __syncthreads();
    if (r==p){
      float ip = 1.0f / sPiv;
      float* brow = isA ? browA : browR;
#pragma unroll
      for (int i=0;i<32;i++){ own[i] *= ip; brow[cb+i] = own[i]; }
    } else if (sub==(p>>5)){
      fcol[r] = own[p&31];
    }
    __syncthreads();
    if (r != p){
      float f = fcol[r];
      const float* brow = isA ? browA : browR;
#pragma unroll
      for (int i=0;i<32;i++) own[i] = fmaf(-f, brow[cb+i], own[i]);
    }
  }
  if (!isA){
#pragma unroll
    for (int i=0;i<32;i++){
      dst [(size_t)r*128 + cb + i] = own[i];
      dstT[(size_t)(cb+i)*128 + r] = own[i];
    }
  }
}

// ---------------------------------------------------------------------------
// Block Gauss-Jordan pivot step (everything between invert and rank-update):
//  blocks [0,nb): j-th 128-col chunk of pivot row:
//     j==k: M[k][k] := P ; Rt[k-slice] := PT
//     else: C = P*M[k][j] (fp32) -> M[k][j] and transposed into Rt
//  blocks [nb,2nb-1): save U[i] := M[i][k] and zero it (i != k)
// ---------------------------------------------------------------------------
__global__ __launch_bounds__(256) void pivot_prep_kernel(
    float* __restrict__ M, int n, int k,
    const float* __restrict__ P, const float* __restrict__ PT,
    float* __restrict__ U, float* __restrict__ Rt)
{
  __shared__ float Ps[16][132];
  __shared__ float Ms[16][132];
  const int nb = n >> 7;
  const int tid = threadIdx.x;
  const int bx = blockIdx.x;

  if (bx >= nb){                      // ---- save + zero column block k
    int i = bx - nb; if (i >= k) i++;
    float* src = M + ((size_t)(i<<7))*n + ((size_t)k<<7);
    for (int q=tid; q<4096; q+=256){
      int r = q>>5, c4 = (q&31)<<2;
      float4 v = *(const float4*)&src[(size_t)r*n + c4];
      *(float4*)&U[((size_t)((i<<7)+r))*128 + c4] = v;
      float4 z; z.x=0.f; z.y=0.f; z.z=0.f; z.w=0.f;
      *(float4*)&src[(size_t)r*n + c4] = z;
    }
    return;
  }
  const int j = bx;
  float* rowk = M + ((size_t)(k<<7))*n;
  if (j == k){                        // ---- pivot block: P / PT copies
    for (int q=tid; q<4096; q+=256){
      int r = q>>5, c4 = (q&31)<<2;
      *(float4*)&rowk[(size_t)r*n + (k<<7) + c4] = *(const float4*)&P[(r<<7)+c4];
      *(float4*)&Rt[((size_t)(k<<7))*128 + (q<<2)] = *(const float4*)&PT[q<<2];
    }
    return;
  }
  // ---- C = P * M[k][j] (fp32), dual store
  const float* Mk = rowk + ((size_t)j<<7);
  const int tx = tid&15, ty = tid>>4;
  float acc[8][8];
#pragma unroll
  for (int i=0;i<8;i++)
#pragma unroll
    for (int jj=0;jj<8;jj++) acc[i][jj]=0.0f;
  for (int kk=0; kk<128; kk+=16){
#pragma unroll
    for (int l=0;l<2;l++){
      int idx = tid + (l<<8);
      { int r = idx>>2, q = idx&3;
        float4 v = *(const float4*)&P[(r<<7) + kk + (q<<2)];
        Ps[(q<<2)+0][r]=v.x; Ps[(q<<2)+1][r]=v.y; Ps[(q<<2)+2][r]=v.z; Ps[(q<<2)+3][r]=v.w; }
      { int kq = idx>>5, c = (idx&31)<<2;
        *(float4*)&Ms[kq][c] = *(const float4*)&Mk[(size_t)(kk+kq)*n + c]; }
    }
    __syncthreads();
#pragma unroll
    for (int kq=0;kq<16;kq++){
      float a[8], b[8];
      *(float4*)&a[0] = *(const float4*)&Ps[kq][(ty<<3)];
      *(float4*)&a[4] = *(const float4*)&Ps[kq][(ty<<3)+4];
      *(float4*)&b[0] = *(const float4*)&Ms[kq][(tx<<3)];
      *(float4*)&b[4] = *(const float4*)&Ms[kq][(tx<<3)+4];
#pragma unroll
      for (int i=0;i<8;i++)
#pragma unroll
        for (int jj=0;jj<8;jj++) acc[i][jj] = fmaf(a[i], b[jj], acc[i][jj]);
    }
    __syncthreads();
  }
#pragma unroll
  for (int i=0;i<8;i++){
    int r_ = (ty<<3)+i;
#pragma unroll
    for (int jj=0;jj<8;jj++){
      int c_ = (tx<<3)+jj;
      float v = acc[i][jj];
      rowk[(size_t)r_*n + (j<<7) + c_] = v;
      Rt[((size_t)((j<<7)+c_))*128 + r_] = v;
    }
  }
}

// ---------------------------------------------------------------------------
// small kernels
// ---------------------------------------------------------------------------
__global__ void sumsq_kernel(const float* __restrict__ w, int n, float* __restrict__ acc){
  float s = 0.0f;
  for (int i = blockIdx.x*blockDim.x + threadIdx.x; i < n; i += gridDim.x*blockDim.x){
    float v = w[i]; s = fmaf(v, v, s);
  }
#pragma unroll
  for (int o=32;o;o>>=1) s += __shfl_xor(s, o);
  if ((threadIdx.x & 63) == 0) atomicAdd(acc, s);
}

__global__ void scales_kernel(float* scal, const float* a0, const float* a1,
                              const float* a2, const float* a3){
  if (threadIdx.x==0 && blockIdx.x==0){
    float s;
    s = a0[0]/sqrtf(scal[0]); scal[4]=s; scal[8]=s*s;
    s = a1[0]/sqrtf(scal[1]); scal[5]=s; scal[9]=s*s;
    s = a2[0]/sqrtf(scal[2]); scal[6]=s; scal[10]=s*s;
    s = a3[0]/sqrtf(scal[3]); scal[7]=s; scal[11]=s*s;
  }
}

__global__ void build_mm_kernel(const float* __restrict__ W, const float* __restrict__ scal,
                                float* __restrict__ Mo){
  int j = (blockIdx.x<<4) + (threadIdx.x&15);
  int i = (blockIdx.y<<4) + (threadIdx.x>>4);
  float s = scal[5];
  float a = s*(W[((size_t)i<<12)+j] - W[((size_t)j<<12)+i]);
  Mo[((size_t)i<<12)+j] = ((i==j)?1.0f:0.0f) + a;
}

__global__ void build_rect_kernel(const float* __restrict__ W, int ldw, int transw, int n,
      const float* __restrict__ G, const float* __restrict__ scal, int sidx,
      float* __restrict__ Mo){
  int j = (blockIdx.x<<4)+(threadIdx.x&15);
  int i = (blockIdx.y<<4)+(threadIdx.x>>4);
  float s = scal[sidx];
  float wij = transw ? W[(size_t)j*ldw+i] : W[(size_t)i*ldw+j];
  float wji = transw ? W[(size_t)i*ldw+j] : W[(size_t)j*ldw+i];
  Mo[(size_t)i*n + j] = ((i==j)?1.0f:0.0f) + s*(wij - wji) + G[(size_t)i*n + j];
}

// dst = 2*X - I
template<typename TD>
__global__ void qtop_kernel(const float* __restrict__ X, int n,
                            TD* __restrict__ dst, int ldd){
  int j = blockIdx.x*blockDim.x + threadIdx.x;
  int i = blockIdx.y;
  if (j<n) storeS(&dst[(size_t)i*ldd+j],
                  2.0f*X[(size_t)i*n+j] - ((i==j)?1.0f:0.0f));
}

// fp32 tiled transpose: dst[c][r] = src[r][c]; rows,cols % 32 == 0
__global__ void transposeF_kernel(const float* __restrict__ src, int ls,
                                  float* __restrict__ dst, int ld){
  __shared__ float t[32][33];
  int c0 = blockIdx.x<<5, r0 = blockIdx.y<<5;
  int tx = threadIdx.x & 31, ty = threadIdx.x >> 5;
#pragma unroll
  for (int i=0;i<4;i++) t[ty+i*8][tx] = src[(size_t)(r0+ty+i*8)*ls + c0+tx];
  __syncthreads();
#pragma unroll
  for (int i=0;i<4;i++) dst[(size_t)(c0+ty+i*8)*ld + r0+tx] = t[tx][ty+i*8];
}

// A' = [ bf16(h) | bf16(x) | bf16(x - bf16(x)) ]  (8192 x 2176)
__global__ void pack_A_kernel(const float* __restrict__ h, const float* __restrict__ x,
                              bf16_t* __restrict__ Ap){
  int c = blockIdx.x*blockDim.x + threadIdx.x;
  int m = blockIdx.y;
  if (c >= 2176) return;
  float v;
  if (c < 128)       v = h[(size_t)m*128 + c];
  else if (c < 1152) v = x[(size_t)m*1024 + (c-128)];
  else {
    float xv = x[(size_t)m*1024 + (c-1152)];
    v = xv - bf2f(f2bf(xv));
  }
  Ap[(size_t)m*2176 + c] = f2bf(v);
}

__global__ void dup_kernel(bf16_t* __restrict__ Bp){
  int c = blockIdx.x*blockDim.x + threadIdx.x;   // 0..1023
  int r = blockIdx.y;
  Bp[(size_t)r*2176 + 1152 + c] = Bp[(size_t)r*2176 + 128 + c];
}

__global__ void addvec_kernel(const float* __restrict__ a, const float* __restrict__ b,
                              float* __restrict__ c, int n){
  int i = blockIdx.x*blockDim.x + threadIdx.x;
  if (i<n) c[i] = a[i] + b[i];
}

// simplex-with-floor projection: one wave per row of 128; 30 Newton iters.
__global__ __launch_bounds__(256) void project_kernel(
    const float* __restrict__ ft, const float* __restrict__ h, float* __restrict__ out){
  int row  = (blockIdx.x<<2) + (threadIdx.x>>6);
  int lane = threadIdx.x & 63;
  const float* fr = ft + ((size_t)row<<7);
  const float* hr = h  + ((size_t)row<<7);
  float f0 = fr[lane], f1 = fr[lane+64];
  float l0 = -ALPHA_1*(expf(SIGMA_1*hr[lane])   - 1.0f);
  float l1 = -ALPHA_1*(expf(SIGMA_1*hr[lane+64])- 1.0f);
  float s = f0 + f1;
#pragma unroll
  for (int o=32;o;o>>=1) s += __shfl_xor(s, o);
  float lam = s * (1.0f/128.0f);
  for (int it=0; it<30; it++){
    float a0 = f0 - lam, a1 = f1 - lam;
    float g = fmaxf(a0,l0) + fmaxf(a1,l1);
    float c = (a0>l0 ? 1.0f:0.0f) + (a1>l1 ? 1.0f:0.0f);
#pragma unroll
    for (int o=32;o;o>>=1){ g += __shfl_xor(g,o); c += __shfl_xor(c,o); }
    lam += g / fmaxf(c, 1.0f);
  }
  out[((size_t)row<<7)+lane]    = fmaxf(f0-lam, l0);
  out[((size_t)row<<7)+lane+64] = fmaxf(f1-lam, l1);
}

// ---------------------------------------------------------------------------
// host-side helpers (enqueue only)
// ---------------------------------------------------------------------------
template<typename TC, int RELU>
static inline void mfma_nt(hipStream_t st, int Mm, int Nn, int Kk,
    const bf16_t* A, int lda, const bf16_t* B, int ldb, TC* C, int ldc,
    const float* bias){
  dim3 grid(Nn>>7, Mm>>7);
  mfma_nt_kernel<TC,RELU><<<grid, 256, 0, st>>>(Mm,Nn,Kk,A,lda,B,ldb,C,ldc,bias);
}

template<typename TC>
static inline void fgemm(hipStream_t st, int Mm, int Nn, int Kk,
    const float* A, int lda, const float* Bt, int ldb, TC* C, int ldc,
    float alpha, const float* aptr, float beta){
  dim3 grid(Nn>>7, Mm>>7);
  fgemm_nt_kernel<TC><<<grid, 256, 0, st>>>(Mm,Nn,Kk,A,lda,Bt,ldb,C,ldc,
                                            alpha,aptr,beta, 1<<30);
}

// In-place block Gauss-Jordan inverse: M (n x n) -> M^-1. 3 launches/step.
static void gj_inverse(hipStream_t st, float* M, int n,
                       float* P, float* PT, float* U, float* Rt){
  int nb = n >> 7;
  for (int k=0;k<nb;k++){
    invert128_kernel<<<1,1024,0,st>>>(M + ((size_t)(k<<7))*n + (k<<7), n, P, PT);
    pivot_prep_kernel<<<2*nb-1, 256, 0, st>>>(M, n, k, P, PT, U, Rt);
    dim3 grid(nb, nb-1);   // skip row-block k
    fgemm_nt_kernel<float><<<grid, 256, 0, st>>>(n, n, 128, U, 128, Rt, 128,
                                                 M, n, -1.0f, nullptr, 1.0f, k);
  }
}

extern "C" void kernel_launch(void* const* d_in, const int* in_sizes, int n_in,
                              void* d_out, int out_size, void* d_ws, size_t ws_size,
                              hipStream_t stream){
  (void)in_sizes; (void)n_in; (void)out_size; (void)ws_size;
  const float* h    = (const float*)d_in[0];   // 8192x128
  const float* x    = (const float*)d_in[1];   // 8192x1024
  const float* Whm  = (const float*)d_in[2];   // 4096x128
  const float* bhm  = (const float*)d_in[3];
  const float* ahm  = (const float*)d_in[4];
  const float* Wmm  = (const float*)d_in[5];   // 4096x4096
  const float* bmm  = (const float*)d_in[6];
  const float* amm  = (const float*)d_in[7];
  const float* Wmh  = (const float*)d_in[8];   // 128x4096
  const float* bmh  = (const float*)d_in[9];
  const float* amh  = (const float*)d_in[10];
  const float* Wux  = (const float*)d_in[11];  // 4096x1024
  const float* bux  = (const float*)d_in[12];
  const float* auxs = (const float*)d_in[13];
  float* out = (float*)d_out;

  // ---- workspace (~183 MiB peak; 189 MiB proven safe) ----
  char* wp = (char*)d_ws;
  auto alloc = [&](size_t bytes)->void*{
    void* p = (void*)wp; wp += (bytes + 255) & ~(size_t)255; return p; };
  float*  scal   = (float*)alloc(4096);
  float*  Ghm    = (float*)alloc((size_t)128*128*4);
  float*  Gmh    = (float*)alloc((size_t)128*128*4);
  float*  Mhm    = (float*)alloc((size_t)128*128*4);
  float*  Mmh    = (float*)alloc((size_t)128*128*4);
  float*  P128   = (float*)alloc((size_t)128*128*4);
  float*  PT128  = (float*)alloc((size_t)128*128*4);
  float*  U      = (float*)alloc((size_t)4096*128*4);     // 2 MiB (GJ col save)
  float*  Rt     = (float*)alloc((size_t)4096*128*4);     // 2 MiB (GJ scaled row^T)
  bf16_t* Qmh_b  = (bf16_t*)alloc((size_t)128*4096*2);    // 1 MiB
  float*  bsum   = (float*)alloc((size_t)4096*4);
  bf16_t* Bp     = (bf16_t*)alloc((size_t)4096*2176*2);   // 17 MiB [Qhm|Qux|Qux_dup]
  float*  R1     = (float*)alloc((size_t)4096*4096*4);    // 64 MiB
  float*  R2     = (float*)alloc((size_t)4096*4096*4);    // 64 MiB
  bf16_t* Qmmb   = (bf16_t*)alloc((size_t)4096*4096*2);   // 32 MiB
  // lifetime aliases:
  float*  VTh  = U;                             // 128x3968 (phase 2 only)
  float*  WmhTv= Rt;                            // 3968x128 (phase 3 only)
  float*  Mmm  = R1;                            // I+A_mm -> inverse (GJ in place)
  bf16_t* Ap   = (bf16_t*)R1;                   // packed A' (after qtop)
  bf16_t* z2   = (bf16_t*)R1;                   // GEMM2 out
  float*  Gux  = R2;                            // phase-1 carve of R2:
  float*  Mux  = R2 + (size_t)1024*1024;        //   -> becomes X_ux in place
  float*  VT   = R2 + (size_t)2*1024*1024;      //   12 MiB (1024x3072)
  float*  XuxT = R2 + (size_t)5*1024*1024;      //   4 MiB
  bf16_t* z    = (bf16_t*)R2;                   // GEMM1 out
  float*  ftl  = R2;                            // GEMM3 out (z dead)

  // ---- phase 0: scales s = a/||W||_F
  hipMemsetAsync(scal, 0, 16*sizeof(float), stream);
  sumsq_kernel<<<512,256,0,stream>>>(Whm, 4096*128,  scal+0);
  sumsq_kernel<<<512,256,0,stream>>>(Wmm, 4096*4096, scal+1);
  sumsq_kernel<<<512,256,0,stream>>>(Wmh, 128*4096,  scal+2);
  sumsq_kernel<<<512,256,0,stream>>>(Wux, 4096*1024, scal+3);
  scales_kernel<<<1,1,0,stream>>>(scal, ahm, amm, amh, auxs);

  // ---- phase 1: ux (1024) -> Bp cols [128,1152)
  transposeF_kernel<<<dim3(32,96),256,0,stream>>>(Wux+(size_t)1024*1024, 1024, VT, 3072);
  fgemm<float>(stream, 1024,1024,3072, VT,3072, VT,3072, Gux,1024, 1.0f,&scal[11], 0.0f);
  build_rect_kernel<<<dim3(64,64),256,0,stream>>>(Wux,1024,0,1024, Gux, scal,7, Mux);
  gj_inverse(stream, Mux, 1024, P128, PT128, U, Rt);      // Mux := (I+A)^-1
  transposeF_kernel<<<dim3(32,32),256,0,stream>>>(Mux, 1024, XuxT, 1024);
  qtop_kernel<bf16_t><<<dim3(4,1024),256,0,stream>>>(Mux, 1024, Bp+128, 2176);
  fgemm<bf16_t>(stream, 3072,1024,1024, Wux+(size_t)1024*1024,1024, XuxT,1024,
                Bp+(size_t)1024*2176+128, 2176, -2.0f,&scal[7], 0.0f);

  // ---- phase 2: hm (128) -> Bp cols [0,128)
  transposeF_kernel<<<dim3(4,124),256,0,stream>>>(Whm+128*128, 128, VTh, 3968);
  fgemm<float>(stream, 128,128,3968, VTh,3968, VTh,3968, Ghm,128, 1.0f,&scal[8], 0.0f);
  build_rect_kernel<<<dim3(8,8),256,0,stream>>>(Whm,128,0,128, Ghm, scal,4, Mhm);
  invert128_kernel<<<1,1024,0,stream>>>(Mhm,128,P128,PT128);
  qtop_kernel<bf16_t><<<dim3(1,128),256,0,stream>>>(P128, 128, Bp, 2176);
  fgemm<bf16_t>(stream, 3968,128,128, Whm+128*128,128, PT128,128,
                Bp+(size_t)128*2176, 2176, -2.0f,&scal[4], 0.0f);

  // ---- phase 3: mh (via W_mh^T) -> Qmh_b (128x4096)
  fgemm<float>(stream, 128,128,3968, Wmh+128,4096, Wmh+128,4096, Gmh,128,
               1.0f,&scal[10], 0.0f);
  build_rect_kernel<<<dim3(8,8),256,0,stream>>>(Wmh,4096,1,128, Gmh, scal,6, Mmh);
  invert128_kernel<<<1,1024,0,stream>>>(Mmh,128,P128,PT128);
  qtop_kernel<bf16_t><<<dim3(1,128),256,0,stream>>>(PT128, 128, Qmh_b, 4096);
  transposeF_kernel<<<dim3(124,4),256,0,stream>>>(Wmh+128, 4096, WmhTv, 128);
  fgemm<bf16_t>(stream, 128,3968,128, PT128,128, WmhTv,128,
                Qmh_b+128, 4096, -2.0f,&scal[6], 0.0f);

  // ---- phase 4: mm (4096): in-place GJ inverse in R1, then Q = 2X - I
  build_mm_kernel<<<dim3(256,256),256,0,stream>>>(Wmm, scal, Mmm);
  gj_inverse(stream, Mmm, 4096, P128, PT128, U, Rt);
  qtop_kernel<bf16_t><<<dim3(16,4096),256,0,stream>>>(Mmm, 4096, Qmmb, 4096);
  // R1 now dead -> Ap; R2 free -> z.

  // ---- phase 5: pack A', finish B', bias sum
  pack_A_kernel<<<dim3(9,8192),256,0,stream>>>(h, x, Ap);
  dup_kernel<<<dim3(4,4096),256,0,stream>>>(Bp);
  addvec_kernel<<<16,256,0,stream>>>(bhm, bux, bsum, 4096);

  // ---- phases 6-8: forward (bf16 MFMA)
  mfma_nt<bf16_t,1>(stream, 8192,4096,2176, Ap,2176, Bp,2176, z,4096, bsum);
  mfma_nt<bf16_t,1>(stream, 8192,4096,4096, z,4096, Qmmb,4096, z2,4096, bmm);
  mfma_nt<float,0>(stream, 8192, 128,4096, z2,4096, Qmh_b,4096, ftl,128, bmh);

  // ---- phase 9: projection
  project_kernel<<<2048,256,0,stream>>>(ftl, h, out);
}